// Round 9
// baseline (394.154 us; speedup 1.0000x reference)
//
#include <hip/hip_runtime.h>
#include <hip/hip_bf16.h>
#include <cstdint>
#include <cstddef>

// Problem constants
#define NSEQ 4096
#define MDIM 1024
// band: |i-j| < 250 -> row-tile ti needs col-tiles [ti-2, ti+2]
// banded layout (Eband bf16 = exp(logits), attT fp8 x16): row i, col c = j - 128*((i>>7)-2), width 640
// fp8 scaling: attn weights x64, attT x16, y stored x8; MLP kept bf16 for accuracy.
// GEMM operand rule: A = matrix indexing the OUTPUT'S MINOR DIM.
// MFMA: MX-scaled mfma_f32_16x16x128_f8f6f4, unit scales (0x7F=2^0), 2x fp8 rate.
// r7: counted-vmcnt pipeline -9.3us. r8 lesson: A-direct-from-global WITHOUT
//   one-tile-ahead prefetch exposes full L2 latency per K-tile (MfmaUtil 27.9->15.7%,
//   +37us) even though bank conflicts halved as predicted. r9: keep the LDS bypass
//   (B-only staging, 32KB) but prefetch A(t+1) into a REGISTER double-buffer during
//   compute(t). Queue sim (in-order, per-wave): steady wait point outstanding =
//   [B(t)4 | A(t+1)8 | B(t+1)4] -> vmcnt(12) retires exactly B(t); A(t) was drained
//   by compiler's tracked vmcnt(4) at prev iter's a8=a8n copy (after MFMAs -> free).
//   Last iter: vmcnt(0). Barriers identical to r7 (leading: B(t) visible; trailing:
//   WAR on buf^1). A-fragment bytes bit-identical to the old LDS path.
// r4 lesson: 128^2 MLP tile -> grid collapse. MLP = dbuf 64^2 k_gemm64.

typedef __attribute__((ext_vector_type(8))) short short8;
typedef __attribute__((ext_vector_type(4))) float f32x4;
typedef __attribute__((ext_vector_type(2))) long long2v;
typedef __attribute__((ext_vector_type(8))) int int8v;
typedef __attribute__((ext_vector_type(4))) int int4v;

typedef const __attribute__((address_space(1))) void gvoid_t;
typedef __attribute__((address_space(3))) void lvoid_t;

__device__ __forceinline__ unsigned short f2b(float x) {
  union { float f; unsigned int u; } a; a.f = x;
  unsigned int r = (a.u + 0x7fffu + ((a.u >> 16) & 1u)) >> 16;
  return (unsigned short)r;
}
__device__ __forceinline__ float b2f(unsigned short u) {
  union { float f; unsigned int u32; } a; a.u32 = ((unsigned int)u) << 16;
  return a.f;
}
__device__ __forceinline__ unsigned char f2e4(float x) {
  return (unsigned char)(__builtin_amdgcn_cvt_pk_fp8_f32(x, x, 0, false) & 0xff);
}
__device__ __forceinline__ unsigned int f2e4x4(float a, float b, float c, float d) {
  unsigned int lo = __builtin_amdgcn_cvt_pk_fp8_f32(a, b, 0, false);
  return (unsigned int)__builtin_amdgcn_cvt_pk_fp8_f32(c, d, lo, true);
}

__device__ __forceinline__ int8v pack32(const unsigned char* p0,
                                        const unsigned char* p1) {
  int4v lo = *(const int4v*)p0;
  int4v hi = *(const int4v*)p1;
  int8v r;
  r[0] = lo[0]; r[1] = lo[1]; r[2] = lo[2]; r[3] = lo[3];
  r[4] = hi[0]; r[5] = hi[1]; r[6] = hi[2]; r[7] = hi[3];
  return r;
}

// -------- merged cvt: Wq..Wo (x64)->fp8, ka/kb/kc->bf16, x1..x3->fp8, zero sums ----
__global__ __launch_bounds__(256) void k_cvt_all(
    const float* __restrict__ s0, const float* __restrict__ s1,
    const float* __restrict__ s2, const float* __restrict__ s3,
    const float* __restrict__ s4, const float* __restrict__ s5,
    const float* __restrict__ s6,
    const float* __restrict__ xa, const float* __restrict__ xb,
    const float* __restrict__ xc,
    unsigned char* __restrict__ Wf8, unsigned short* __restrict__ Wmlp,
    unsigned char* __restrict__ Xdst, float* __restrict__ sums) {
  int idx = blockIdx.x * 256 + threadIdx.x;  // chunk of 4 floats
  if (idx < 1048576) {  // Wq,Wk,Wv,Wo fp8 x64
    int seg = idx >> 18, local = idx & 262143;
    const float* src = (seg == 0) ? s0 : (seg == 1) ? s1 : (seg == 2) ? s2 : s3;
    float4 v = *(const float4*)(src + (size_t)local * 4);
    *(unsigned int*)(Wf8 + (size_t)idx * 4) =
        f2e4x4(v.x * 64.f, v.y * 64.f, v.z * 64.f, v.w * 64.f);
  } else if (idx < 1458176) {  // ka,kb,kc bf16
    int i2 = idx - 1048576;
    const float* src; int local;
    if (i2 < 262144) { src = s4; local = i2; }
    else if (i2 < 393216) { src = s5; local = i2 - 262144; }
    else { src = s6; local = i2 - 393216; }
    float4 v = *(const float4*)(src + (size_t)local * 4);
    ushort4 o; o.x = f2b(v.x); o.y = f2b(v.y); o.z = f2b(v.z); o.w = f2b(v.w);
    *(ushort4*)(Wmlp + (size_t)i2 * 4) = o;
  } else if (idx < 4603904) {  // x1..x3 fp8
    int i2 = idx - 1458176;   // 0 .. 3*2^20-1
    int seg = i2 >> 20, local = i2 & 1048575;
    const float* src = (seg == 0) ? xa : (seg == 1) ? xb : xc;
    float4 v = *(const float4*)(src + (size_t)local * 4);
    *(unsigned int*)(Xdst + (size_t)i2 * 4) = f2e4x4(v.x, v.y, v.z, v.w);
  } else {  // zero softmax denominators (12288 floats)
    int i3 = idx - 4603904;   // 0..3071
    *(float4*)(sums + (size_t)i3 * 4) = make_float4(0.f, 0.f, 0.f, 0.f);
  }
}

// -------- fp8 GEMM core: A reg-prefetched from global, B LDS counted-vmcnt --------
// BK=128. B staging: global_load_lds 16B; LDS row=128B=8 slots; slot s holds chunk (s-r)&7.
// A fragments: per-lane 32B contiguous global loads, double-buffered in regs,
// prefetched ONE TILE AHEAD (r8's exposed-latency bug fixed).
// OKIND: 1=bf16(8B, DO_EXP optional), 2=fp8(dword).
// MODE 3: QKV. by<8: Q; 8..15: K; >=16: VT. MODE 1: logits+rowsums.
// MODE 2: y=attT@V (K window). MODE 0: Wo.
template <int MODE, int OKIND, int DO_EXP>
__device__ __forceinline__ void gemm_core(
    const unsigned char* __restrict__ A, int lda,
    const unsigned char* __restrict__ B, int ldb,
    void* __restrict__ Cout, void* __restrict__ Cout2, int ldc,
    int K, float alpha,
    const unsigned char* __restrict__ A1, const unsigned char* __restrict__ A2,
    float* __restrict__ sums_out, unsigned char* __restrict__ smem) {
  int bx = blockIdx.x, by = blockIdx.y;
  const unsigned char* Ab;
  const unsigned char* Bb;
  void* Cdst = Cout;
  int k0 = 0, k1 = K, b_koff = 0;
  int ldce = ldc;
  int rbase, cbase;
  int ldae = lda, ldbe = ldb;
  if constexpr (MODE == 0) {
    Ab = A + (size_t)by * 128 * lda;      // Wo rows
    Bb = B + (size_t)bx * 128 * ldb;      // y rows
    rbase = bx * 128; cbase = by * 128;
  } else if constexpr (MODE == 3) {
    if (by < 16) {
      Ab = A + (size_t)by * 128 * lda;    // Wq|Wk contiguous rows
      Bb = B + (size_t)bx * 128 * ldb;    // X rows
      if (by >= 8) Cdst = Cout2;
      rbase = bx * 128; cbase = (by & 7) * 128;
    } else {
      Ab = B + (size_t)bx * 128 * ldb;                 // X rows (qc = x)
      Bb = A1 + (size_t)(by - 16) * 128 * 1024;        // Wv rows (qr = wv)
      Cdst = (void*)const_cast<unsigned char*>(A2);    // VT [1024,12288]
      rbase = (by - 16) * 128; cbase = bx * 128;
      ldce = 3 * NSEQ;
    }
  } else if constexpr (MODE == 1) {
    int s = bx >> 5, ti = bx & 31;
    int bt = ti + by - 2;                        // validity checked by caller
    Ab = A + (size_t)(s * 32 + bt) * 128 * lda;  // K rows (qc = band col)
    Bb = B + (size_t)bx * 128 * ldb;             // Q rows (qr = i)
    rbase = bx * 128; cbase = by * 128;          // ldce = 640
  } else {  // MODE == 2
    int s = bx >> 5, ti = bx & 31;
    Ab = A + (size_t)by * 128 * lda + s * NSEQ;   // VT rows (qc = v), col offset s*4096
    const unsigned char* Bbase = (s == 0) ? B : ((s == 1) ? A1 : A2);
    Bb = Bbase + (size_t)ti * 128 * 640;          // attT banded rows (qr = i)
    ldbe = 640;
    int lo = ti - 2; if (lo < 0) lo = 0;
    int hi = ti + 3; if (hi > 32) hi = 32;
    k0 = lo * 128; k1 = hi * 128;
    b_koff = (ti - 2) * 128;
    rbase = bx * 128; cbase = by * 128;
  }

  const int t = threadIdx.x;
  const int l = t & 63;
  const int w = t >> 6;
  const int fr = l & 15;
  const int quad = l >> 4;
  const int wm = (w >> 1) * 64;
  const int wn = (w & 1) * 64;
  const int fq4 = quad * 4;

  // B staging: 4 insts per wave; inst j covers rows w*32+j*8 .. +7
  int srow[4], scg[4], sloff[4];
#pragma unroll
  for (int j = 0; j < 4; j++) {
    srow[j] = w * 32 + j * 8 + (l >> 3);
    scg[j] = ((l & 7) - srow[j]) & 7;       // global chunk for LDS slot l&7
    sloff[j] = (w * 32 + j * 8) * 128 + l * 16;
  }

  // A direct base: lane's fragment row base + K-block offset
  const unsigned char* Al = Ab + (size_t)(wm + fr) * ldae + quad * 32;

  f32x4 acc[4][4];
#pragma unroll
  for (int m = 0; m < 4; m++)
#pragma unroll
    for (int n = 0; n < 4; n++) acc[m][n] = (f32x4){0.f, 0.f, 0.f, 0.f};

  const int c0 = quad * 2;   // first 16B chunk of this lane's K-block (B side)
  const int nt = (k1 - k0) >> 7;

  // prologue: A(0) -> regs (8 loads), B(0) -> LDS buf 0 (4 gload_lds); all in flight
  int8v a8[4], a8n[4];
#pragma unroll
  for (int m = 0; m < 4; m++) {
    const unsigned char* p = Al + (size_t)(m * 16) * ldae + k0;
    a8[m] = pack32(p, p + 16);
  }
  {
    int kb = k0 - b_koff;
#pragma unroll
    for (int j = 0; j < 4; j++)
      __builtin_amdgcn_global_load_lds(
          (gvoid_t*)(Bb + (size_t)srow[j] * ldbe + kb + scg[j] * 16),
          (lvoid_t*)(smem + sloff[j]), 16, 0, 0);
  }

  for (int tt = 0; tt < nt; tt++) {
    int kk = k0 + tt * 128;
    if (tt + 1 < nt) {
      // prefetch A(t+1) into the register double-buffer (latency hides under
      // this iteration's ds_reads + MFMAs; drained by the tracked wait at the
      // a8=a8n copy AFTER the MFMAs)
#pragma unroll
      for (int m = 0; m < 4; m++) {
        const unsigned char* p = Al + (size_t)(m * 16) * ldae + kk + 128;
        a8n[m] = pack32(p, p + 16);
      }
      // issue B tile t+1 into the other buffer (WAR-safe via prior trailing barrier)
      int kb = kk + 128 - b_koff;
      unsigned char* Bn = smem + ((tt + 1) & 1) * 16384;
#pragma unroll
      for (int j = 0; j < 4; j++)
        __builtin_amdgcn_global_load_lds(
            (gvoid_t*)(Bb + (size_t)srow[j] * ldbe + kb + scg[j] * 16),
            (lvoid_t*)(Bn + sloff[j]), 16, 0, 0);
      __builtin_amdgcn_sched_barrier(0);
      // steady-state outstanding: [B(t) 4 | A(t+1) 8 | B(t+1) 4] (A(t) already
      // drained by prev iter's copy-wait). Retire the 4 oldest = B(t); 12 fly on.
      asm volatile("s_waitcnt vmcnt(12)" ::: "memory");
    } else {
      // last iter: outstanding = B(t) 4 only. Drain.
      asm volatile("s_waitcnt vmcnt(0)" ::: "memory");
    }
    asm volatile("s_barrier" ::: "memory");   // B tile t fully in LDS, all waves

    const unsigned char* Bsc = smem + (tt & 1) * 16384;
    int8v b8[4];
#pragma unroll
    for (int n = 0; n < 4; n++) {
      int r = wn + n * 16 + fr;
      int s0i = (c0 + r) & 7, s1i = (s0i + 1) & 7;
      b8[n] = pack32(Bsc + r * 128 + s0i * 16, Bsc + r * 128 + s1i * 16);
    }
#pragma unroll
    for (int m = 0; m < 4; m++)
#pragma unroll
      for (int n = 0; n < 4; n++)
        acc[m][n] = __builtin_amdgcn_mfma_scale_f32_16x16x128_f8f6f4(
            a8[m], b8[n], acc[m][n], 0, 0, 0, 0x7F7F7F7F, 0, 0x7F7F7F7F);
    asm volatile("s_barrier" ::: "memory");   // all reads of buf[tt&1] retired
    if (tt + 1 < nt) {
      // rotate register buffer; compiler's tracked vmcnt wait for a8n lands here,
      // after the MFMAs -> A(t+1) had the whole compute phase to arrive.
#pragma unroll
      for (int m = 0; m < 4; m++) a8[m] = a8n[m];
    }
  }

  // direct-store epilogue; MODE 1 also accumulates the in-band row-sum of exp
  float rowsum[4] = {0.f, 0.f, 0.f, 0.f};
  const int jb = ((bx & 31) - 2) * 128;   // used only when MODE==1
#pragma unroll
  for (int m = 0; m < 4; m++) {
#pragma unroll
    for (int n = 0; n < 4; n++) {
      int oc = cbase + wm + m * 16 + fq4;
      int orow = rbase + wn + n * 16 + fr;
      float v0 = acc[m][n][0] * alpha, v1 = acc[m][n][1] * alpha;
      float v2 = acc[m][n][2] * alpha, v3 = acc[m][n][3] * alpha;
      if constexpr (OKIND == 1) {
        if constexpr (DO_EXP) {
          v0 = __expf(v0); v1 = __expf(v1); v2 = __expf(v2); v3 = __expf(v3);
          if constexpr (MODE == 1) {
            int d0 = (orow & 4095) - (jb + oc);   // i - j for element 0
            rowsum[n] += ((unsigned)(d0 + 249) < 499u ? v0 : 0.f)
                       + ((unsigned)(d0 + 248) < 499u ? v1 : 0.f)
                       + ((unsigned)(d0 + 247) < 499u ? v2 : 0.f)
                       + ((unsigned)(d0 + 246) < 499u ? v3 : 0.f);
          }
        }
        ushort4 o; o.x = f2b(v0); o.y = f2b(v1); o.z = f2b(v2); o.w = f2b(v3);
        *(uint2*)((unsigned short*)Cdst + (size_t)orow * ldce + oc) = *(uint2*)&o;
      } else {
        *(unsigned int*)((unsigned char*)Cdst + (size_t)orow * ldce + oc) =
            f2e4x4(v0, v1, v2, v3);
      }
    }
  }
  if constexpr (MODE == 1 && DO_EXP) {
    // lanes {fr, fr+16, fr+32, fr+48} hold the same rows; reduce across quads
#pragma unroll
    for (int n = 0; n < 4; n++) {
      float sv = rowsum[n];
      sv += __shfl_xor(sv, 16);
      sv += __shfl_xor(sv, 32);
      if (quad == 0) {
        int orow = rbase + wn + n * 16 + fr;
        atomicAdd(sums_out + orow, sv);
      }
    }
  }
}

// QKV fp8
__global__ __launch_bounds__(256) void k_qkv(
    const unsigned char* __restrict__ A, const unsigned char* __restrict__ B,
    void* __restrict__ Cout, void* __restrict__ Cout2, float alpha,
    const unsigned char* __restrict__ A1, const unsigned char* __restrict__ A2) {
  __shared__ unsigned char smem[2 * 128 * 128];  // 32 KB: 2 B-bufs
  gemm_core<3, 2, 0>(A, 1024, B, 1024, Cout, Cout2, 1024, 1024, alpha,
                     A1, A2, nullptr, smem);
}

// logits -> Eband (exp) + fused band row-sums
__global__ __launch_bounds__(256) void k_logits(
    const unsigned char* __restrict__ A, const unsigned char* __restrict__ B,
    void* __restrict__ Cout, float alpha, float* __restrict__ sums) {
  int ti = blockIdx.x & 31;
  int bt = ti + (int)blockIdx.y - 2;
  if (bt < 0 || bt >= 32) return;   // whole-block, before any barrier
  __shared__ unsigned char smem[2 * 128 * 128];
  gemm_core<1, 1, 1>(A, 1024, B, 1024, Cout, nullptr, 640, 1024, alpha,
                     nullptr, nullptr, sums, smem);
}

// y = attT @ V (banded K window)
__global__ __launch_bounds__(256) void k_av(
    const unsigned char* __restrict__ A, const unsigned char* __restrict__ B,
    void* __restrict__ Cout, float alpha,
    const unsigned char* __restrict__ A1, const unsigned char* __restrict__ A2) {
  __shared__ unsigned char smem[2 * 128 * 128];
  gemm_core<2, 2, 0>(A, 3 * NSEQ, B, 640, Cout, nullptr, 1024, NSEQ, alpha,
                     A1, A2, nullptr, smem);
}

// yo = y @ Wo^T (bf16 out, no exp)
__global__ __launch_bounds__(256) void k_wo(
    const unsigned char* __restrict__ A, const unsigned char* __restrict__ B,
    void* __restrict__ Cout, float alpha) {
  __shared__ unsigned char smem[2 * 128 * 128];
  gemm_core<0, 1, 0>(A, 1024, B, 1024, Cout, nullptr, 1024, 1024, alpha,
                     nullptr, nullptr, nullptr, smem);
}

// -------- small bf16 GEMM: 64x64 tile, BK=64, 2-phase dbuf --------
// A = weight (qc dim), B = activation (qr dim).
__global__ __launch_bounds__(256) void k_gemm64(
    const unsigned short* __restrict__ A, int lda,
    const unsigned short* __restrict__ B, int ldb,
    void* __restrict__ Cout, int ldc, int K,
    const float* __restrict__ bias, int relu, int out_bf16) {
  __shared__ unsigned short smem[4 * 64 * 64];  // 32 KB: 2 bufs x (A | B)
  int bx = blockIdx.x, by = blockIdx.y;
  const unsigned short* Ab = A + (size_t)by * 64 * lda;   // weight rows
  const unsigned short* Bb = B + (size_t)bx * 64 * ldb;   // activation rows
  int rbase = bx * 64, cbase = by * 64;

  const int t = threadIdx.x;
  const int l = t & 63;
  const int w = t >> 6;
  const int fr = l & 15;
  const int quad = l >> 4;
  const int wm = (w & 1) * 32;
  const int wn = (w >> 1) * 32;
  const int fq4 = quad * 4;

  int srow[2], scg[2], sloff[2];
#pragma unroll
  for (int j = 0; j < 2; j++) {
    srow[j] = w * 16 + j * 8 + (l >> 3);
    scg[j] = ((l & 7) - srow[j]) & 7;
    sloff[j] = (w * 16 + j * 8) * 64 + l * 8;
  }

  f32x4 acc[2][2];
#pragma unroll
  for (int m = 0; m < 2; m++)
#pragma unroll
    for (int n = 0; n < 2; n++) acc[m][n] = (f32x4){0.f, 0.f, 0.f, 0.f};

  const int nt = K >> 6;

  // prologue: stage tile 0 -> buf 0
#pragma unroll
  for (int j = 0; j < 2; j++)
    __builtin_amdgcn_global_load_lds(
        (gvoid_t*)(Ab + (size_t)srow[j] * lda + scg[j] * 8),
        (lvoid_t*)(smem + sloff[j]), 16, 0, 0);
#pragma unroll
  for (int j = 0; j < 2; j++)
    __builtin_amdgcn_global_load_lds(
        (gvoid_t*)(Bb + (size_t)srow[j] * ldb + scg[j] * 8),
        (lvoid_t*)(smem + 4096 + sloff[j]), 16, 0, 0);

  for (int tt = 0; tt < nt; tt++) {
    __syncthreads();   // buf[tt&1] ready; all waves done reading buf[(tt+1)&1]
    if (tt + 1 < nt) {
      int kk = (tt + 1) * 64;
      unsigned short* Asn = smem + ((tt + 1) & 1) * 8192;
#pragma unroll
      for (int j = 0; j < 2; j++)
        __builtin_amdgcn_global_load_lds(
            (gvoid_t*)(Ab + (size_t)srow[j] * lda + kk + scg[j] * 8),
            (lvoid_t*)(Asn + sloff[j]), 16, 0, 0);
#pragma unroll
      for (int j = 0; j < 2; j++)
        __builtin_amdgcn_global_load_lds(
            (gvoid_t*)(Bb + (size_t)srow[j] * ldb + kk + scg[j] * 8),
            (lvoid_t*)(Asn + 4096 + sloff[j]), 16, 0, 0);
    }
    const unsigned short* Asc = smem + (tt & 1) * 8192;
    const unsigned short* Bsc = Asc + 4096;
#pragma unroll
    for (int s = 0; s < 2; s++) {
      short8 af[2], bf[2];
#pragma unroll
      for (int m = 0; m < 2; m++) {
        int r = wm + m * 16 + fr;
        int slot = (s * 4 + quad + r) & 7;
        af[m] = *(const short8*)(Asc + r * 64 + slot * 8);
      }
#pragma unroll
      for (int n = 0; n < 2; n++) {
        int r = wn + n * 16 + fr;
        int slot = (s * 4 + quad + r) & 7;
        bf[n] = *(const short8*)(Bsc + r * 64 + slot * 8);
      }
#pragma unroll
      for (int m = 0; m < 2; m++)
#pragma unroll
        for (int n = 0; n < 2; n++)
          acc[m][n] = __builtin_amdgcn_mfma_f32_16x16x32_bf16(af[m], bf[n], acc[m][n], 0, 0, 0);
    }
  }

#pragma unroll
  for (int m = 0; m < 2; m++) {
#pragma unroll
    for (int n = 0; n < 2; n++) {
      int oc = cbase + wm + m * 16 + fq4;
      int orow = rbase + wn + n * 16 + fr;
      float4 bv = bias ? *(const float4*)(bias + oc) : make_float4(0.f, 0.f, 0.f, 0.f);
      float v0 = acc[m][n][0] + bv.x, v1 = acc[m][n][1] + bv.y;
      float v2 = acc[m][n][2] + bv.z, v3 = acc[m][n][3] + bv.w;
      if (relu) {
        v0 = fmaxf(v0, 0.f); v1 = fmaxf(v1, 0.f);
        v2 = fmaxf(v2, 0.f); v3 = fmaxf(v3, 0.f);
      }
      if (out_bf16) {
        ushort4 o; o.x = f2b(v0); o.y = f2b(v1); o.z = f2b(v2); o.w = f2b(v3);
        *(uint2*)((unsigned short*)Cout + (size_t)orow * ldc + oc) = *(uint2*)&o;
      } else {
        *(float4*)((float*)Cout + (size_t)orow * ldc + oc) = make_float4(v0, v1, v2, v3);
      }
    }
  }
}

// -------- build banded attT (fp8 x16): attT_s[i][j - 128*((i>>7)-2)] = 16*att[j][i] --------
__global__ __launch_bounds__(256) void k_build_attT(const unsigned short* __restrict__ Eband,
                                                    const float* __restrict__ sums,
                                                    unsigned char* __restrict__ t0,
                                                    unsigned char* __restrict__ t1,
                                                    unsigned char* __restrict__ t2) {
  int byy = blockIdx.y;
  int s = byy >> 5, ti = byy & 31;       // i tile (attT rows), local
  int tj = ti + (int)blockIdx.x - 2;     // j tile
  if (tj < 0 || tj >= 32) return;
  unsigned char* dst = (s == 0) ? t0 : ((s == 1) ? t1 : t2);
  __shared__ unsigned char T[128][132];  // T[i_loc][j_loc]
  int t = threadIdx.x;
  int c0 = (ti - tj + 2) * 128;  // Eband col base for rows j reading i-tile ti
  int colg = (t & 31) * 4;       // i_loc
  for (int jj = t >> 5; jj < 128; jj += 8) {
    int jg = s * NSEQ + tj * 128 + jj;
    float inv = 16.f / sums[jg];
    ushort4 v = *(const ushort4*)&Eband[(size_t)jg * 640 + c0 + colg];
    float vv[4] = {b2f(v.x), b2f(v.y), b2f(v.z), b2f(v.w)};
#pragma unroll
    for (int q = 0; q < 4; q++) {
      int i = ti * 128 + colg + q;
      int d = i - (tj * 128 + jj);
      float a = (d < 250 && d > -250) ? vv[q] * inv : 0.f;
      T[colg + q][jj] = f2e4(a);
    }
  }
  __syncthreads();
  int jb0 = (tj - ti + 2) * 128;  // banded col base in attT rows of tile ti
  for (int ii = t >> 5; ii < 128; ii += 8) {
    size_t o = (size_t)(ti * 128 + ii) * 640 + jb0 + colg;
    *(unsigned int*)(dst + o) = *(const unsigned int*)&T[ii][colg];
  }
}

// -------- write full fp32 att (stream 0 / x1), zeros outside band --------
__global__ __launch_bounds__(256) void k_write_att(const unsigned short* __restrict__ Eband,
                                                   const float* __restrict__ sums,
                                                   float* __restrict__ att) {
  int i = blockIdx.x;
  int ti = i >> 7, cbase = (ti - 2) * 128;
  int jlo = i - 249; if (jlo < 0) jlo = 0;
  int jhi = i + 249; if (jhi > NSEQ - 1) jhi = NSEQ - 1;
  float inv = 1.f / sums[i];
  const unsigned short* L = Eband + (size_t)i * 640;
  float* arow = att + (size_t)i * NSEQ;
  for (int j0 = threadIdx.x * 4; j0 < NSEQ; j0 += 1024) {
    float ov[4];
#pragma unroll
    for (int q = 0; q < 4; q++) {
      int j = j0 + q;
      ov[q] = (j >= jlo && j <= jhi) ? b2f(L[j - cbase]) * inv : 0.f;
    }
    *(float4*)(arow + j0) = make_float4(ov[0], ov[1], ov[2], ov[3]);
  }
}

// -------- residual + LayerNorm (ddof=1, eps on std) for 3 streams, sum -> bf16 --------
__global__ __launch_bounds__(256) void k_ln3(const unsigned short* __restrict__ yo,
                                             const float* __restrict__ x1,
                                             const float* __restrict__ x2,
                                             const float* __restrict__ x3,
                                             const float* __restrict__ g,
                                             const float* __restrict__ b,
                                             unsigned short* __restrict__ ysum_b) {
  int i = blockIdx.x, t = threadIdx.x;
  int w = t >> 6, lane = t & 63;
  __shared__ float red[8];
  const float* xs[3] = {x1, x2, x3};
  float4 gg = *(const float4*)(g + t * 4);
  float4 bb = *(const float4*)(b + t * 4);
  float acc[4] = {0.f, 0.f, 0.f, 0.f};
  for (int s = 0; s < 3; s++) {
    ushort4 yv = *(const ushort4*)(yo + ((size_t)(s * NSEQ + i)) * MDIM + t * 4);
    float4 xx = *(const float4*)(xs[s] + (size_t)i * MDIM + t * 4);
    float v[4] = {b2f(yv.x) + xx.x, b2f(yv.y) + xx.y, b2f(yv.z) + xx.z, b2f(yv.w) + xx.w};
    float s1 = v[0] + v[1] + v[2] + v[3];
    float s2 = v[0]*v[0] + v[1]*v[1] + v[2]*v[2] + v[3]*v[3];
    for (int off = 32; off; off >>= 1) { s1 += __shfl_xor(s1, off); s2 += __shfl_xor(s2, off); }
    __syncthreads();
    if (lane == 0) { red[w] = s1; red[4 + w] = s2; }
    __syncthreads();
    float S1 = red[0] + red[1] + red[2] + red[3];
    float S2 = red[4] + red[5] + red[6] + red[7];
    float mean = S1 * (1.f / 1024.f);
    float var = (S2 - S1 * mean) * (1.f / 1023.f);
    float rstd = 1.f / (sqrtf(var) + 1e-6f);
    acc[0] += gg.x * (v[0] - mean) * rstd + bb.x;
    acc[1] += gg.y * (v[1] - mean) * rstd + bb.y;
    acc[2] += gg.z * (v[2] - mean) * rstd + bb.z;
    acc[3] += gg.w * (v[3] - mean) * rstd + bb.w;
  }
  ushort4 o;
  o.x = f2b(acc[0]); o.y = f2b(acc[1]); o.z = f2b(acc[2]); o.w = f2b(acc[3]);
  *(ushort4*)(ysum_b + (size_t)i * MDIM + t * 4) = o;
}

// -------- final: LN(128, gkc/bkc) -> dot(kd_w) + kd_b -> sigmoid --------
__global__ __launch_bounds__(128) void k_final(const float* __restrict__ h3,
                                               const float* __restrict__ g,
                                               const float* __restrict__ b,
                                               const float* __restrict__ kdw,
                                               const float* __restrict__ kdb,
                                               float* __restrict__ yout) {
  int i = blockIdx.x, t = threadIdx.x;
  float v = h3[(size_t)i * 128 + t];
  float s1 = v, s2 = v * v;
  for (int off = 32; off; off >>= 1) { s1 += __shfl_xor(s1, off); s2 += __shfl_xor(s2, off); }
  __shared__ float red[4];
  int w = t >> 6, lane = t & 63;
  if (lane == 0) { red[w] = s1; red[2 + w] = s2; }
  __syncthreads();
  float S1 = red[0] + red[1], S2 = red[2] + red[3];
  float mean = S1 * (1.f / 128.f);
  float var = (S2 - S1 * mean) * (1.f / 127.f);
  float rstd = 1.f / (sqrtf(var) + 1e-6f);
  float ln = g[t] * (v - mean) * rstd + b[t];
  float p = ln * kdw[t];
  for (int off = 32; off; off >>= 1) p += __shfl_xor(p, off);
  __syncthreads();
  if (lane == 0) red[w] = p;
  __syncthreads();
  if (t == 0) {
    float z = red[0] + red[1] + kdb[0];
    yout[i] = 1.f / (1.f + __expf(-z));
  }
}

extern "C" void kernel_launch(void* const* d_in, const int* in_sizes, int n_in,
                              void* d_out, int out_size, void* d_ws, size_t ws_size,
                              hipStream_t stream) {
  const float* x1 = (const float*)d_in[0];
  const float* x2 = (const float*)d_in[1];
  const float* x3 = (const float*)d_in[2];
  const float* Wq = (const float*)d_in[3];
  const float* Wk = (const float*)d_in[4];
  const float* Wv = (const float*)d_in[5];
  const float* Wo = (const float*)d_in[6];
  const float* ka_w = (const float*)d_in[7];
  const float* ka_b = (const float*)d_in[8];
  const float* kb_w = (const float*)d_in[9];
  const float* kb_b = (const float*)d_in[10];
  const float* kc_w = (const float*)d_in[11];
  const float* kc_b = (const float*)d_in[12];
  const float* kd_w = (const float*)d_in[13];
  const float* kd_b = (const float*)d_in[14];
  const float* g13 = (const float*)d_in[15];
  const float* b13 = (const float*)d_in[16];
  const float* gkc = (const float*)d_in[17];
  const float* bkc = (const float*)d_in[18];

  float* y_out = (float*)d_out;
  float* att_out = y_out + NSEQ;  // [4096,4096] fp32

  char* ws = (char*)d_ws;
  size_t off = 0;
  auto alloc = [&](size_t bytes) -> void* {
    void* p = ws + off;
    off += (bytes + 255) & ~(size_t)255;
    return p;
  };
  const size_t NM = (size_t)3 * NSEQ * MDIM;  // 12.6M elems
  // fp8 attention weights, contiguous: Wq|Wk|Wv|Wo (x64 scaled)
  unsigned char* Wf = (unsigned char*)alloc(4 * 1048576);
  // bf16 MLP weights, contiguous: ka|kb|kc
  unsigned short* Wmlp = (unsigned short*)alloc((1048576 + 524288 + 65536) * 2);
  unsigned char* Xf = (unsigned char*)alloc(NM);      // later: yb fp8, then h1b bf16
  unsigned char* Qf = (unsigned char*)alloc(NM);      // yo bf16 spans Qf+Kf; later h2b
  unsigned char* Kf = (unsigned char*)alloc(NM);
  unsigned char* VTf = (unsigned char*)alloc(NM);     // later: ysum_b bf16 (8MB)
  unsigned short* Eband = (unsigned short*)alloc((size_t)3 * NSEQ * 640 * 2);
  float* sums = (float*)alloc((size_t)3 * NSEQ * 4);
  unsigned char* aT0 = (unsigned char*)alloc((size_t)NSEQ * 640);  // later: h3 f32
  unsigned char* aT1 = (unsigned char*)alloc((size_t)NSEQ * 640);
  unsigned char* aT2 = (unsigned char*)alloc((size_t)NSEQ * 640);
  // weight sub-pointers
  unsigned char* Wv_f = Wf + 2097152;
  unsigned char* Wo_f = Wf + 3145728;
  unsigned short* ka_b16 = Wmlp;
  unsigned short* kb_b16 = Wmlp + 1048576;
  unsigned short* kc_b16 = Wmlp + 1572864;
  // aliases (lifetimes disjoint)
  unsigned char* yb = Xf;                       // fp8 [12288,1024] = 8*y
  unsigned short* yo = (unsigned short*)Qf;     // bf16 [12288,1024] spans Qf..Kf
  unsigned short* ysum_b = (unsigned short*)VTf;// bf16 [4096,1024]
  unsigned short* h1b = (unsigned short*)Xf;    // bf16 [4096,1024]
  unsigned short* h2b = (unsigned short*)Qf;    // bf16 [4096,512]
  float* h3 = (float*)aT0;                      // f32 [4096,128]

  // all conversions + sums zero-init in one dispatch
  k_cvt_all<<<17996, 256, 0, stream>>>(Wq, Wk, Wv, Wo, ka_w, kb_w, kc_w,
                                       x1, x2, x3, Wf, Wmlp, Xf, sums);

  // merged Q+K+VT fp8: Q/K: A=Wq|Wk, B=X; VT: A=X, B=Wv
  k_qkv<<<dim3(96, 24), 256, 0, stream>>>(Wf, Xf, Qf, Kf, 1.f / 64.f, Wv_f, VTf);
  // banded logits -> E = exp(0.06 * Q.K) bf16 [12288,640] + fused band row-sums
  k_logits<<<dim3(96, 5), 256, 0, stream>>>(Kf, Qf, Eband, 0.06f, sums);
  k_build_attT<<<dim3(5, 96), 256, 0, stream>>>(Eband, sums, aT0, aT1, aT2);
  // yb = 8*y: A=VT (v minor), B=attT banded; (16att)@V * 0.5, fp8 out
  k_av<<<dim3(96, 8), 256, 0, stream>>>(VTf, aT0, yb, 0.5f, aT1, aT2);
  k_write_att<<<4096, 256, 0, stream>>>(Eband, sums, att_out);
  // yo = y @ Wo^T (bf16 out): A=Wo, B=y; (8y)@(64Wo) * 1/512
  k_wo<<<dim3(96, 8), 256, 0, stream>>>(Wo_f, yb, yo, 1.f / 512.f);
  // residual + LN + 3-stream sum -> bf16
  k_ln3<<<4096, 256, 0, stream>>>(yo, x1, x2, x3, g13, b13, ysum_b);

  // MLP head (bf16, 64x64 tiles dbuf, A=weight)
  k_gemm64<<<dim3(64, 16), 256, 0, stream>>>(ka_b16, 1024, ysum_b, 1024, h1b, 1024,
                                             1024, ka_b, 0, 1);
  k_gemm64<<<dim3(64, 8), 256, 0, stream>>>(kb_b16, 1024, h1b, 1024, h2b, 512,
                                            1024, kb_b, 0, 1);
  k_gemm64<<<dim3(64, 2), 256, 0, stream>>>(kc_b16, 512, h2b, 512, h3, 128,
                                            512, kc_b, 1, 0);
  k_final<<<4096, 128, 0, stream>>>(h3, gkc, bkc, kd_w, kd_b, y_out);
}

// Round 10
// 327.918 us; speedup vs baseline: 1.2020x; 1.2020x over previous
//
#include <hip/hip_runtime.h>
#include <hip/hip_bf16.h>
#include <cstdint>
#include <cstddef>

// Problem constants
#define NSEQ 4096
#define MDIM 1024
// band: |i-j| < 250 -> row-tile ti needs col-tiles [ti-2, ti+2]
// banded layout (Eband bf16 = exp(logits), attT fp8 x16): row i, col c = j - 128*((i>>7)-2), width 640
// fp8 scaling: attn weights x64, attT x16, y stored x8; MLP kept bf16 for accuracy.
// GEMM operand rule: A = matrix indexing the OUTPUT'S MINOR DIM.
// MFMA: MX-scaled mfma_f32_16x16x128_f8f6f4, unit scales (0x7F=2^0), 2x fp8 rate.
// r7 (best, 325.9us): counted-vmcnt pipeline, A+B gload_lds, 64KB LDS.
// r8/r9 lesson: A-from-global (LDS bypass) stalled at 95-97us regardless of reg
//   prefetch -> "memory"-clobbered asm waitcnt makes the waitcnt pass conservative
//   (asm may read LDS written by gload_lds -> forced drains). REVERTED.
// r10: exact r7 structure; ONLY change = m201 barrier idiom: no-clobber
//   asm s_waitcnt vmcnt(N) + raw __builtin_amdgcn_s_barrier() + sched_barrier(0)
//   fences (rule #18). Ordering: issue(t+1) | SB0 | vmcnt(8) | SB0 | s_barrier |
//   SB0 | ds_read+MFMA | SB0 | s_barrier.
// r4 lesson: 128^2 MLP tile -> grid collapse. MLP = dbuf 64^2 k_gemm64.

typedef __attribute__((ext_vector_type(8))) short short8;
typedef __attribute__((ext_vector_type(4))) float f32x4;
typedef __attribute__((ext_vector_type(2))) long long2v;
typedef __attribute__((ext_vector_type(8))) int int8v;
typedef __attribute__((ext_vector_type(4))) int int4v;

typedef const __attribute__((address_space(1))) void gvoid_t;
typedef __attribute__((address_space(3))) void lvoid_t;

__device__ __forceinline__ unsigned short f2b(float x) {
  union { float f; unsigned int u; } a; a.f = x;
  unsigned int r = (a.u + 0x7fffu + ((a.u >> 16) & 1u)) >> 16;
  return (unsigned short)r;
}
__device__ __forceinline__ float b2f(unsigned short u) {
  union { float f; unsigned int u32; } a; a.u32 = ((unsigned int)u) << 16;
  return a.f;
}
__device__ __forceinline__ unsigned char f2e4(float x) {
  return (unsigned char)(__builtin_amdgcn_cvt_pk_fp8_f32(x, x, 0, false) & 0xff);
}
__device__ __forceinline__ unsigned int f2e4x4(float a, float b, float c, float d) {
  unsigned int lo = __builtin_amdgcn_cvt_pk_fp8_f32(a, b, 0, false);
  return (unsigned int)__builtin_amdgcn_cvt_pk_fp8_f32(c, d, lo, true);
}

__device__ __forceinline__ int8v pack32(const unsigned char* p0,
                                        const unsigned char* p1) {
  int4v lo = *(const int4v*)p0;
  int4v hi = *(const int4v*)p1;
  int8v r;
  r[0] = lo[0]; r[1] = lo[1]; r[2] = lo[2]; r[3] = lo[3];
  r[4] = hi[0]; r[5] = hi[1]; r[6] = hi[2]; r[7] = hi[3];
  return r;
}

// -------- merged cvt: Wq..Wo (x64)->fp8, ka/kb/kc->bf16, x1..x3->fp8, zero sums ----
__global__ __launch_bounds__(256) void k_cvt_all(
    const float* __restrict__ s0, const float* __restrict__ s1,
    const float* __restrict__ s2, const float* __restrict__ s3,
    const float* __restrict__ s4, const float* __restrict__ s5,
    const float* __restrict__ s6,
    const float* __restrict__ xa, const float* __restrict__ xb,
    const float* __restrict__ xc,
    unsigned char* __restrict__ Wf8, unsigned short* __restrict__ Wmlp,
    unsigned char* __restrict__ Xdst, float* __restrict__ sums) {
  int idx = blockIdx.x * 256 + threadIdx.x;  // chunk of 4 floats
  if (idx < 1048576) {  // Wq,Wk,Wv,Wo fp8 x64
    int seg = idx >> 18, local = idx & 262143;
    const float* src = (seg == 0) ? s0 : (seg == 1) ? s1 : (seg == 2) ? s2 : s3;
    float4 v = *(const float4*)(src + (size_t)local * 4);
    *(unsigned int*)(Wf8 + (size_t)idx * 4) =
        f2e4x4(v.x * 64.f, v.y * 64.f, v.z * 64.f, v.w * 64.f);
  } else if (idx < 1458176) {  // ka,kb,kc bf16
    int i2 = idx - 1048576;
    const float* src; int local;
    if (i2 < 262144) { src = s4; local = i2; }
    else if (i2 < 393216) { src = s5; local = i2 - 262144; }
    else { src = s6; local = i2 - 393216; }
    float4 v = *(const float4*)(src + (size_t)local * 4);
    ushort4 o; o.x = f2b(v.x); o.y = f2b(v.y); o.z = f2b(v.z); o.w = f2b(v.w);
    *(ushort4*)(Wmlp + (size_t)i2 * 4) = o;
  } else if (idx < 4603904) {  // x1..x3 fp8
    int i2 = idx - 1458176;   // 0 .. 3*2^20-1
    int seg = i2 >> 20, local = i2 & 1048575;
    const float* src = (seg == 0) ? xa : (seg == 1) ? xb : xc;
    float4 v = *(const float4*)(src + (size_t)local * 4);
    *(unsigned int*)(Xdst + (size_t)i2 * 4) = f2e4x4(v.x, v.y, v.z, v.w);
  } else {  // zero softmax denominators (12288 floats)
    int i3 = idx - 4603904;   // 0..3071
    *(float4*)(sums + (size_t)i3 * 4) = make_float4(0.f, 0.f, 0.f, 0.f);
  }
}

// -------- fp8 GEMM core (templated), counted-vmcnt pipeline, direct-store --------
// BK=128, global_load_lds 16B staging; LDS row=128B=8 slots; slot s holds chunk (s-r)&7.
// One mfma_scale_f32_16x16x128_f8f6f4 per (m,n) per K-tile, unit scales.
// OKIND: 1=bf16(8B, DO_EXP optional), 2=fp8(dword).
// MODE 3: QKV. by<8: Q; 8..15: K; >=16: VT. MODE 1: logits+rowsums.
// MODE 2: y=attT@V (K window). MODE 0: Wo.
template <int MODE, int OKIND, int DO_EXP>
__device__ __forceinline__ void gemm_core(
    const unsigned char* __restrict__ A, int lda,
    const unsigned char* __restrict__ B, int ldb,
    void* __restrict__ Cout, void* __restrict__ Cout2, int ldc,
    int K, float alpha,
    const unsigned char* __restrict__ A1, const unsigned char* __restrict__ A2,
    float* __restrict__ sums_out, unsigned char* __restrict__ smem) {
  int bx = blockIdx.x, by = blockIdx.y;
  const unsigned char* Ab;
  const unsigned char* Bb;
  void* Cdst = Cout;
  int k0 = 0, k1 = K, b_koff = 0;
  int ldce = ldc;
  int rbase, cbase;
  int ldae = lda, ldbe = ldb;
  if constexpr (MODE == 0) {
    Ab = A + (size_t)by * 128 * lda;      // Wo rows
    Bb = B + (size_t)bx * 128 * ldb;      // y rows
    rbase = bx * 128; cbase = by * 128;
  } else if constexpr (MODE == 3) {
    if (by < 16) {
      Ab = A + (size_t)by * 128 * lda;    // Wq|Wk contiguous rows
      Bb = B + (size_t)bx * 128 * ldb;    // X rows
      if (by >= 8) Cdst = Cout2;
      rbase = bx * 128; cbase = (by & 7) * 128;
    } else {
      Ab = B + (size_t)bx * 128 * ldb;                 // X rows (qc = x)
      Bb = A1 + (size_t)(by - 16) * 128 * 1024;        // Wv rows (qr = wv)
      Cdst = (void*)const_cast<unsigned char*>(A2);    // VT [1024,12288]
      rbase = (by - 16) * 128; cbase = bx * 128;
      ldce = 3 * NSEQ;
    }
  } else if constexpr (MODE == 1) {
    int s = bx >> 5, ti = bx & 31;
    int bt = ti + by - 2;                        // validity checked by caller
    Ab = A + (size_t)(s * 32 + bt) * 128 * lda;  // K rows (qc = band col)
    Bb = B + (size_t)bx * 128 * ldb;             // Q rows (qr = i)
    rbase = bx * 128; cbase = by * 128;          // ldce = 640
  } else {  // MODE == 2
    int s = bx >> 5, ti = bx & 31;
    Ab = A + (size_t)by * 128 * lda + s * NSEQ;   // VT rows (qc = v), col offset s*4096
    const unsigned char* Bbase = (s == 0) ? B : ((s == 1) ? A1 : A2);
    Bb = Bbase + (size_t)ti * 128 * 640;          // attT banded rows (qr = i)
    ldbe = 640;
    int lo = ti - 2; if (lo < 0) lo = 0;
    int hi = ti + 3; if (hi > 32) hi = 32;
    k0 = lo * 128; k1 = hi * 128;
    b_koff = (ti - 2) * 128;
    rbase = bx * 128; cbase = by * 128;
  }

  const int t = threadIdx.x;
  const int l = t & 63;
  const int w = t >> 6;
  const int fr = l & 15;
  const int quad = l >> 4;
  const int wm = (w >> 1) * 64;
  const int wn = (w & 1) * 64;
  const int fq4 = quad * 4;

  // staging: 4 insts per matrix per wave; inst j covers rows w*32+j*8 .. +7
  int srow[4], scg[4], sloff[4];
#pragma unroll
  for (int j = 0; j < 4; j++) {
    srow[j] = w * 32 + j * 8 + (l >> 3);
    scg[j] = ((l & 7) - srow[j]) & 7;       // global chunk for LDS slot l&7
    sloff[j] = (w * 32 + j * 8) * 128 + l * 16;
  }

  f32x4 acc[4][4];
#pragma unroll
  for (int m = 0; m < 4; m++)
#pragma unroll
    for (int n = 0; n < 4; n++) acc[m][n] = (f32x4){0.f, 0.f, 0.f, 0.f};

  const int c0 = quad * 2;   // first 16B chunk of this lane's K-block
  const int nt = (k1 - k0) >> 7;

  // prologue: issue tile 0 -> buf 0 (8 loads/wave, left in flight)
  {
    int kk = k0, kb = kk - b_koff;
#pragma unroll
    for (int j = 0; j < 4; j++)
      __builtin_amdgcn_global_load_lds(
          (gvoid_t*)(Ab + (size_t)srow[j] * ldae + kk + scg[j] * 16),
          (lvoid_t*)(smem + sloff[j]), 16, 0, 0);
#pragma unroll
    for (int j = 0; j < 4; j++)
      __builtin_amdgcn_global_load_lds(
          (gvoid_t*)(Bb + (size_t)srow[j] * ldbe + kb + scg[j] * 16),
          (lvoid_t*)(smem + 16384 + sloff[j]), 16, 0, 0);
  }

  for (int tt = 0; tt < nt; tt++) {
    if (tt + 1 < nt) {
      // issue tile t+1's 8 loads into the other buffer (WAR-safe: prior iter's
      // trailing barrier guaranteed all waves retired their reads of it)
      int kk = k0 + (tt + 1) * 128, kb = kk - b_koff;
      unsigned char* Asn = smem + ((tt + 1) & 1) * 32768;
#pragma unroll
      for (int j = 0; j < 4; j++)
        __builtin_amdgcn_global_load_lds(
            (gvoid_t*)(Ab + (size_t)srow[j] * ldae + kk + scg[j] * 16),
            (lvoid_t*)(Asn + sloff[j]), 16, 0, 0);
#pragma unroll
      for (int j = 0; j < 4; j++)
        __builtin_amdgcn_global_load_lds(
            (gvoid_t*)(Bb + (size_t)srow[j] * ldbe + kb + scg[j] * 16),
            (lvoid_t*)(Asn + 16384 + sloff[j]), 16, 0, 0);
      __builtin_amdgcn_sched_barrier(0);
      // wait only the 8 OLDEST (tile t); tile t+1's 8 stay in flight across the
      // barrier. NO "memory" clobber (r10 fix): clobber made the waitcnt pass
      // conservative (asm may read LDS written by gload_lds -> forced drains).
      asm volatile("s_waitcnt vmcnt(8)");
    } else {
      __builtin_amdgcn_sched_barrier(0);
      asm volatile("s_waitcnt vmcnt(0)");
    }
    __builtin_amdgcn_sched_barrier(0);
    __builtin_amdgcn_s_barrier();            // tile t fully in LDS, all waves
    __builtin_amdgcn_sched_barrier(0);

    const unsigned char* Asc = smem + (tt & 1) * 32768;
    const unsigned char* Bsc = Asc + 16384;
    int8v a8[4], b8[4];
#pragma unroll
    for (int m = 0; m < 4; m++) {
      int r = wm + m * 16 + fr;
      int s0i = (c0 + r) & 7, s1i = (s0i + 1) & 7;
      a8[m] = pack32(Asc + r * 128 + s0i * 16, Asc + r * 128 + s1i * 16);
    }
#pragma unroll
    for (int n = 0; n < 4; n++) {
      int r = wn + n * 16 + fr;
      int s0i = (c0 + r) & 7, s1i = (s0i + 1) & 7;
      b8[n] = pack32(Bsc + r * 128 + s0i * 16, Bsc + r * 128 + s1i * 16);
    }
#pragma unroll
    for (int m = 0; m < 4; m++)
#pragma unroll
      for (int n = 0; n < 4; n++)
        acc[m][n] = __builtin_amdgcn_mfma_scale_f32_16x16x128_f8f6f4(
            a8[m], b8[n], acc[m][n], 0, 0, 0, 0x7F7F7F7F, 0, 0x7F7F7F7F);
    __builtin_amdgcn_sched_barrier(0);
    __builtin_amdgcn_s_barrier();            // all reads of buf[tt&1] retired
  }

  // direct-store epilogue; MODE 1 also accumulates the in-band row-sum of exp
  float rowsum[4] = {0.f, 0.f, 0.f, 0.f};
  const int jb = ((bx & 31) - 2) * 128;   // used only when MODE==1
#pragma unroll
  for (int m = 0; m < 4; m++) {
#pragma unroll
    for (int n = 0; n < 4; n++) {
      int oc = cbase + wm + m * 16 + fq4;
      int orow = rbase + wn + n * 16 + fr;
      float v0 = acc[m][n][0] * alpha, v1 = acc[m][n][1] * alpha;
      float v2 = acc[m][n][2] * alpha, v3 = acc[m][n][3] * alpha;
      if constexpr (OKIND == 1) {
        if constexpr (DO_EXP) {
          v0 = __expf(v0); v1 = __expf(v1); v2 = __expf(v2); v3 = __expf(v3);
          if constexpr (MODE == 1) {
            int d0 = (orow & 4095) - (jb + oc);   // i - j for element 0
            rowsum[n] += ((unsigned)(d0 + 249) < 499u ? v0 : 0.f)
                       + ((unsigned)(d0 + 248) < 499u ? v1 : 0.f)
                       + ((unsigned)(d0 + 247) < 499u ? v2 : 0.f)
                       + ((unsigned)(d0 + 246) < 499u ? v3 : 0.f);
          }
        }
        ushort4 o; o.x = f2b(v0); o.y = f2b(v1); o.z = f2b(v2); o.w = f2b(v3);
        *(uint2*)((unsigned short*)Cdst + (size_t)orow * ldce + oc) = *(uint2*)&o;
      } else {
        *(unsigned int*)((unsigned char*)Cdst + (size_t)orow * ldce + oc) =
            f2e4x4(v0, v1, v2, v3);
      }
    }
  }
  if constexpr (MODE == 1 && DO_EXP) {
    // lanes {fr, fr+16, fr+32, fr+48} hold the same rows; reduce across quads
#pragma unroll
    for (int n = 0; n < 4; n++) {
      float sv = rowsum[n];
      sv += __shfl_xor(sv, 16);
      sv += __shfl_xor(sv, 32);
      if (quad == 0) {
        int orow = rbase + wn + n * 16 + fr;
        atomicAdd(sums_out + orow, sv);
      }
    }
  }
}

// QKV fp8: counted-vmcnt pipelined
__global__ __launch_bounds__(256) void k_qkv(
    const unsigned char* __restrict__ A, const unsigned char* __restrict__ B,
    void* __restrict__ Cout, void* __restrict__ Cout2, float alpha,
    const unsigned char* __restrict__ A1, const unsigned char* __restrict__ A2) {
  __shared__ unsigned char smem[4 * 128 * 128];
  gemm_core<3, 2, 0>(A, 1024, B, 1024, Cout, Cout2, 1024, 1024, alpha,
                     A1, A2, nullptr, smem);
}

// logits -> Eband (exp) + fused band row-sums
__global__ __launch_bounds__(256) void k_logits(
    const unsigned char* __restrict__ A, const unsigned char* __restrict__ B,
    void* __restrict__ Cout, float alpha, float* __restrict__ sums) {
  int ti = blockIdx.x & 31;
  int bt = ti + (int)blockIdx.y - 2;
  if (bt < 0 || bt >= 32) return;   // whole-block, before any barrier
  __shared__ unsigned char smem[4 * 128 * 128];
  gemm_core<1, 1, 1>(A, 1024, B, 1024, Cout, nullptr, 640, 1024, alpha,
                     nullptr, nullptr, sums, smem);
}

// y = attT @ V (banded K window)
__global__ __launch_bounds__(256) void k_av(
    const unsigned char* __restrict__ A, const unsigned char* __restrict__ B,
    void* __restrict__ Cout, float alpha,
    const unsigned char* __restrict__ A1, const unsigned char* __restrict__ A2) {
  __shared__ unsigned char smem[4 * 128 * 128];
  gemm_core<2, 2, 0>(A, 3 * NSEQ, B, 640, Cout, nullptr, 1024, NSEQ, alpha,
                     A1, A2, nullptr, smem);
}

// yo = y @ Wo^T (bf16 out, no exp)
__global__ __launch_bounds__(256) void k_wo(
    const unsigned char* __restrict__ A, const unsigned char* __restrict__ B,
    void* __restrict__ Cout, float alpha) {
  __shared__ unsigned char smem[4 * 128 * 128];
  gemm_core<0, 1, 0>(A, 1024, B, 1024, Cout, nullptr, 1024, 1024, alpha,
                     nullptr, nullptr, nullptr, smem);
}

// -------- small bf16 GEMM: 64x64 tile, BK=64, 2-phase dbuf --------
// A = weight (qc dim), B = activation (qr dim).
__global__ __launch_bounds__(256) void k_gemm64(
    const unsigned short* __restrict__ A, int lda,
    const unsigned short* __restrict__ B, int ldb,
    void* __restrict__ Cout, int ldc, int K,
    const float* __restrict__ bias, int relu, int out_bf16) {
  __shared__ unsigned short smem[4 * 64 * 64];  // 32 KB: 2 bufs x (A | B)
  int bx = blockIdx.x, by = blockIdx.y;
  const unsigned short* Ab = A + (size_t)by * 64 * lda;   // weight rows
  const unsigned short* Bb = B + (size_t)bx * 64 * ldb;   // activation rows
  int rbase = bx * 64, cbase = by * 64;

  const int t = threadIdx.x;
  const int l = t & 63;
  const int w = t >> 6;
  const int fr = l & 15;
  const int quad = l >> 4;
  const int wm = (w & 1) * 32;
  const int wn = (w >> 1) * 32;
  const int fq4 = quad * 4;

  int srow[2], scg[2], sloff[2];
#pragma unroll
  for (int j = 0; j < 2; j++) {
    srow[j] = w * 16 + j * 8 + (l >> 3);
    scg[j] = ((l & 7) - srow[j]) & 7;
    sloff[j] = (w * 16 + j * 8) * 64 + l * 8;
  }

  f32x4 acc[2][2];
#pragma unroll
  for (int m = 0; m < 2; m++)
#pragma unroll
    for (int n = 0; n < 2; n++) acc[m][n] = (f32x4){0.f, 0.f, 0.f, 0.f};

  const int nt = K >> 6;

  // prologue: stage tile 0 -> buf 0
#pragma unroll
  for (int j = 0; j < 2; j++)
    __builtin_amdgcn_global_load_lds(
        (gvoid_t*)(Ab + (size_t)srow[j] * lda + scg[j] * 8),
        (lvoid_t*)(smem + sloff[j]), 16, 0, 0);
#pragma unroll
  for (int j = 0; j < 2; j++)
    __builtin_amdgcn_global_load_lds(
        (gvoid_t*)(Bb + (size_t)srow[j] * ldb + scg[j] * 8),
        (lvoid_t*)(smem + 4096 + sloff[j]), 16, 0, 0);

  for (int tt = 0; tt < nt; tt++) {
    __syncthreads();   // buf[tt&1] ready; all waves done reading buf[(tt+1)&1]
    if (tt + 1 < nt) {
      int kk = (tt + 1) * 64;
      unsigned short* Asn = smem + ((tt + 1) & 1) * 8192;
#pragma unroll
      for (int j = 0; j < 2; j++)
        __builtin_amdgcn_global_load_lds(
            (gvoid_t*)(Ab + (size_t)srow[j] * lda + kk + scg[j] * 8),
            (lvoid_t*)(Asn + sloff[j]), 16, 0, 0);
#pragma unroll
      for (int j = 0; j < 2; j++)
        __builtin_amdgcn_global_load_lds(
            (gvoid_t*)(Bb + (size_t)srow[j] * ldb + kk + scg[j] * 8),
            (lvoid_t*)(Asn + 4096 + sloff[j]), 16, 0, 0);
    }
    const unsigned short* Asc = smem + (tt & 1) * 8192;
    const unsigned short* Bsc = Asc + 4096;
#pragma unroll
    for (int s = 0; s < 2; s++) {
      short8 af[2], bf[2];
#pragma unroll
      for (int m = 0; m < 2; m++) {
        int r = wm + m * 16 + fr;
        int slot = (s * 4 + quad + r) & 7;
        af[m] = *(const short8*)(Asc + r * 64 + slot * 8);
      }
#pragma unroll
      for (int n = 0; n < 2; n++) {
        int r = wn + n * 16 + fr;
        int slot = (s * 4 + quad + r) & 7;
        bf[n] = *(const short8*)(Bsc + r * 64 + slot * 8);
      }
#pragma unroll
      for (int m = 0; m < 2; m++)
#pragma unroll
        for (int n = 0; n < 2; n++)
          acc[m][n] = __builtin_amdgcn_mfma_f32_16x16x32_bf16(af[m], bf[n], acc[m][n], 0, 0, 0);
    }
  }

#pragma unroll
  for (int m = 0; m < 2; m++) {
#pragma unroll
    for (int n = 0; n < 2; n++) {
      int oc = cbase + wm + m * 16 + fq4;
      int orow = rbase + wn + n * 16 + fr;
      float4 bv = bias ? *(const float4*)(bias + oc) : make_float4(0.f, 0.f, 0.f, 0.f);
      float v0 = acc[m][n][0] + bv.x, v1 = acc[m][n][1] + bv.y;
      float v2 = acc[m][n][2] + bv.z, v3 = acc[m][n][3] + bv.w;
      if (relu) {
        v0 = fmaxf(v0, 0.f); v1 = fmaxf(v1, 0.f);
        v2 = fmaxf(v2, 0.f); v3 = fmaxf(v3, 0.f);
      }
      if (out_bf16) {
        ushort4 o; o.x = f2b(v0); o.y = f2b(v1); o.z = f2b(v2); o.w = f2b(v3);
        *(uint2*)((unsigned short*)Cout + (size_t)orow * ldc + oc) = *(uint2*)&o;
      } else {
        *(float4*)((float*)Cout + (size_t)orow * ldc + oc) = make_float4(v0, v1, v2, v3);
      }
    }
  }
}

// -------- build banded attT (fp8 x16): attT_s[i][j - 128*((i>>7)-2)] = 16*att[j][i] --------
__global__ __launch_bounds__(256) void k_build_attT(const unsigned short* __restrict__ Eband,
                                                    const float* __restrict__ sums,
                                                    unsigned char* __restrict__ t0,
                                                    unsigned char* __restrict__ t1,
                                                    unsigned char* __restrict__ t2) {
  int byy = blockIdx.y;
  int s = byy >> 5, ti = byy & 31;       // i tile (attT rows), local
  int tj = ti + (int)blockIdx.x - 2;     // j tile
  if (tj < 0 || tj >= 32) return;
  unsigned char* dst = (s == 0) ? t0 : ((s == 1) ? t1 : t2);
  __shared__ unsigned char T[128][132];  // T[i_loc][j_loc]
  int t = threadIdx.x;
  int c0 = (ti - tj + 2) * 128;  // Eband col base for rows j reading i-tile ti
  int colg = (t & 31) * 4;       // i_loc
  for (int jj = t >> 5; jj < 128; jj += 8) {
    int jg = s * NSEQ + tj * 128 + jj;
    float inv = 16.f / sums[jg];
    ushort4 v = *(const ushort4*)&Eband[(size_t)jg * 640 + c0 + colg];
    float vv[4] = {b2f(v.x), b2f(v.y), b2f(v.z), b2f(v.w)};
#pragma unroll
    for (int q = 0; q < 4; q++) {
      int i = ti * 128 + colg + q;
      int d = i - (tj * 128 + jj);
      float a = (d < 250 && d > -250) ? vv[q] * inv : 0.f;
      T[colg + q][jj] = f2e4(a);
    }
  }
  __syncthreads();
  int jb0 = (tj - ti + 2) * 128;  // banded col base in attT rows of tile ti
  for (int ii = t >> 5; ii < 128; ii += 8) {
    size_t o = (size_t)(ti * 128 + ii) * 640 + jb0 + colg;
    *(unsigned int*)(dst + o) = *(const unsigned int*)&T[ii][colg];
  }
}

// -------- write full fp32 att (stream 0 / x1), zeros outside band --------
__global__ __launch_bounds__(256) void k_write_att(const unsigned short* __restrict__ Eband,
                                                   const float* __restrict__ sums,
                                                   float* __restrict__ att) {
  int i = blockIdx.x;
  int ti = i >> 7, cbase = (ti - 2) * 128;
  int jlo = i - 249; if (jlo < 0) jlo = 0;
  int jhi = i + 249; if (jhi > NSEQ - 1) jhi = NSEQ - 1;
  float inv = 1.f / sums[i];
  const unsigned short* L = Eband + (size_t)i * 640;
  float* arow = att + (size_t)i * NSEQ;
  for (int j0 = threadIdx.x * 4; j0 < NSEQ; j0 += 1024) {
    float ov[4];
#pragma unroll
    for (int q = 0; q < 4; q++) {
      int j = j0 + q;
      ov[q] = (j >= jlo && j <= jhi) ? b2f(L[j - cbase]) * inv : 0.f;
    }
    *(float4*)(arow + j0) = make_float4(ov[0], ov[1], ov[2], ov[3]);
  }
}

// -------- residual + LayerNorm (ddof=1, eps on std) for 3 streams, sum -> bf16 --------
__global__ __launch_bounds__(256) void k_ln3(const unsigned short* __restrict__ yo,
                                             const float* __restrict__ x1,
                                             const float* __restrict__ x2,
                                             const float* __restrict__ x3,
                                             const float* __restrict__ g,
                                             const float* __restrict__ b,
                                             unsigned short* __restrict__ ysum_b) {
  int i = blockIdx.x, t = threadIdx.x;
  int w = t >> 6, lane = t & 63;
  __shared__ float red[8];
  const float* xs[3] = {x1, x2, x3};
  float4 gg = *(const float4*)(g + t * 4);
  float4 bb = *(const float4*)(b + t * 4);
  float acc[4] = {0.f, 0.f, 0.f, 0.f};
  for (int s = 0; s < 3; s++) {
    ushort4 yv = *(const ushort4*)(yo + ((size_t)(s * NSEQ + i)) * MDIM + t * 4);
    float4 xx = *(const float4*)(xs[s] + (size_t)i * MDIM + t * 4);
    float v[4] = {b2f(yv.x) + xx.x, b2f(yv.y) + xx.y, b2f(yv.z) + xx.z, b2f(yv.w) + xx.w};
    float s1 = v[0] + v[1] + v[2] + v[3];
    float s2 = v[0]*v[0] + v[1]*v[1] + v[2]*v[2] + v[3]*v[3];
    for (int off = 32; off; off >>= 1) { s1 += __shfl_xor(s1, off); s2 += __shfl_xor(s2, off); }
    __syncthreads();
    if (lane == 0) { red[w] = s1; red[4 + w] = s2; }
    __syncthreads();
    float S1 = red[0] + red[1] + red[2] + red[3];
    float S2 = red[4] + red[5] + red[6] + red[7];
    float mean = S1 * (1.f / 1024.f);
    float var = (S2 - S1 * mean) * (1.f / 1023.f);
    float rstd = 1.f / (sqrtf(var) + 1e-6f);
    acc[0] += gg.x * (v[0] - mean) * rstd + bb.x;
    acc[1] += gg.y * (v[1] - mean) * rstd + bb.y;
    acc[2] += gg.z * (v[2] - mean) * rstd + bb.z;
    acc[3] += gg.w * (v[3] - mean) * rstd + bb.w;
  }
  ushort4 o;
  o.x = f2b(acc[0]); o.y = f2b(acc[1]); o.z = f2b(acc[2]); o.w = f2b(acc[3]);
  *(ushort4*)(ysum_b + (size_t)i * MDIM + t * 4) = o;
}

// -------- final: LN(128, gkc/bkc) -> dot(kd_w) + kd_b -> sigmoid --------
__global__ __launch_bounds__(128) void k_final(const float* __restrict__ h3,
                                               const float* __restrict__ g,
                                               const float* __restrict__ b,
                                               const float* __restrict__ kdw,
                                               const float* __restrict__ kdb,
                                               float* __restrict__ yout) {
  int i = blockIdx.x, t = threadIdx.x;
  float v = h3[(size_t)i * 128 + t];
  float s1 = v, s2 = v * v;
  for (int off = 32; off; off >>= 1) { s1 += __shfl_xor(s1, off); s2 += __shfl_xor(s2, off); }
  __shared__ float red[4];
  int w = t >> 6, lane = t & 63;
  if (lane == 0) { red[w] = s1; red[2 + w] = s2; }
  __syncthreads();
  float S1 = red[0] + red[1], S2 = red[2] + red[3];
  float mean = S1 * (1.f / 128.f);
  float var = (S2 - S1 * mean) * (1.f / 127.f);
  float rstd = 1.f / (sqrtf(var) + 1e-6f);
  float ln = g[t] * (v - mean) * rstd + b[t];
  float p = ln * kdw[t];
  for (int off = 32; off; off >>= 1) p += __shfl_xor(p, off);
  __syncthreads();
  if (lane == 0) red[w] = p;
  __syncthreads();
  if (t == 0) {
    float z = red[0] + red[1] + kdb[0];
    yout[i] = 1.f / (1.f + __expf(-z));
  }
}

extern "C" void kernel_launch(void* const* d_in, const int* in_sizes, int n_in,
                              void* d_out, int out_size, void* d_ws, size_t ws_size,
                              hipStream_t stream) {
  const float* x1 = (const float*)d_in[0];
  const float* x2 = (const float*)d_in[1];
  const float* x3 = (const float*)d_in[2];
  const float* Wq = (const float*)d_in[3];
  const float* Wk = (const float*)d_in[4];
  const float* Wv = (const float*)d_in[5];
  const float* Wo = (const float*)d_in[6];
  const float* ka_w = (const float*)d_in[7];
  const float* ka_b = (const float*)d_in[8];
  const float* kb_w = (const float*)d_in[9];
  const float* kb_b = (const float*)d_in[10];
  const float* kc_w = (const float*)d_in[11];
  const float* kc_b = (const float*)d_in[12];
  const float* kd_w = (const float*)d_in[13];
  const float* kd_b = (const float*)d_in[14];
  const float* g13 = (const float*)d_in[15];
  const float* b13 = (const float*)d_in[16];
  const float* gkc = (const float*)d_in[17];
  const float* bkc = (const float*)d_in[18];

  float* y_out = (float*)d_out;
  float* att_out = y_out + NSEQ;  // [4096,4096] fp32

  char* ws = (char*)d_ws;
  size_t off = 0;
  auto alloc = [&](size_t bytes) -> void* {
    void* p = ws + off;
    off += (bytes + 255) & ~(size_t)255;
    return p;
  };
  const size_t NM = (size_t)3 * NSEQ * MDIM;  // 12.6M elems
  // fp8 attention weights, contiguous: Wq|Wk|Wv|Wo (x64 scaled)
  unsigned char* Wf = (unsigned char*)alloc(4 * 1048576);
  // bf16 MLP weights, contiguous: ka|kb|kc
  unsigned short* Wmlp = (unsigned short*)alloc((1048576 + 524288 + 65536) * 2);
  unsigned char* Xf = (unsigned char*)alloc(NM);      // later: yb fp8, then h1b bf16
  unsigned char* Qf = (unsigned char*)alloc(NM);      // yo bf16 spans Qf+Kf; later h2b
  unsigned char* Kf = (unsigned char*)alloc(NM);
  unsigned char* VTf = (unsigned char*)alloc(NM);     // later: ysum_b bf16 (8MB)
  unsigned short* Eband = (unsigned short*)alloc((size_t)3 * NSEQ * 640 * 2);
  float* sums = (float*)alloc((size_t)3 * NSEQ * 4);
  unsigned char* aT0 = (unsigned char*)alloc((size_t)NSEQ * 640);  // later: h3 f32
  unsigned char* aT1 = (unsigned char*)alloc((size_t)NSEQ * 640);
  unsigned char* aT2 = (unsigned char*)alloc((size_t)NSEQ * 640);
  // weight sub-pointers
  unsigned char* Wv_f = Wf + 2097152;
  unsigned char* Wo_f = Wf + 3145728;
  unsigned short* ka_b16 = Wmlp;
  unsigned short* kb_b16 = Wmlp + 1048576;
  unsigned short* kc_b16 = Wmlp + 1572864;
  // aliases (lifetimes disjoint)
  unsigned char* yb = Xf;                       // fp8 [12288,1024] = 8*y
  unsigned short* yo = (unsigned short*)Qf;     // bf16 [12288,1024] spans Qf..Kf
  unsigned short* ysum_b = (unsigned short*)VTf;// bf16 [4096,1024]
  unsigned short* h1b = (unsigned short*)Xf;    // bf16 [4096,1024]
  unsigned short* h2b = (unsigned short*)Qf;    // bf16 [4096,512]
  float* h3 = (float*)aT0;                      // f32 [4096,128]

  // all conversions + sums zero-init in one dispatch
  k_cvt_all<<<17996, 256, 0, stream>>>(Wq, Wk, Wv, Wo, ka_w, kb_w, kc_w,
                                       x1, x2, x3, Wf, Wmlp, Xf, sums);

  // merged Q+K+VT fp8: Q/K: A=Wq|Wk, B=X; VT: A=X, B=Wv
  k_qkv<<<dim3(96, 24), 256, 0, stream>>>(Wf, Xf, Qf, Kf, 1.f / 64.f, Wv_f, VTf);
  // banded logits -> E = exp(0.06 * Q.K) bf16 [12288,640] + fused band row-sums
  k_logits<<<dim3(96, 5), 256, 0, stream>>>(Kf, Qf, Eband, 0.06f, sums);
  k_build_attT<<<dim3(5, 96), 256, 0, stream>>>(Eband, sums, aT0, aT1, aT2);
  // yb = 8*y: A=VT (v minor), B=attT banded; (16att)@V * 0.5, fp8 out
  k_av<<<dim3(96, 8), 256, 0, stream>>>(VTf, aT0, yb, 0.5f, aT1, aT2);
  k_write_att<<<4096, 256, 0, stream>>>(Eband, sums, att_out);
  // yo = y @ Wo^T (bf16 out): A=Wo, B=y; (8y)@(64Wo) * 1/512
  k_wo<<<dim3(96, 8), 256, 0, stream>>>(Wo_f, yb, yo, 1.f / 512.f);
  // residual + LN + 3-stream sum -> bf16
  k_ln3<<<4096, 256, 0, stream>>>(yo, x1, x2, x3, g13, b13, ysum_b);

  // MLP head (bf16, 64x64 tiles dbuf, A=weight)
  k_gemm64<<<dim3(64, 16), 256, 0, stream>>>(ka_b16, 1024, ysum_b, 1024, h1b, 1024,
                                             1024, ka_b, 0, 1);
  k_gemm64<<<dim3(64, 8), 256, 0, stream>>>(kb_b16, 1024, h1b, 1024, h2b, 512,
                                            1024, kb_b, 0, 1);
  k_gemm64<<<dim3(64, 2), 256, 0, stream>>>(kc_b16, 512, h2b, 512, h3, 128,
                                            512, kc_b, 1, 0);
  k_final<<<4096, 128, 0, stream>>>(h3, gkc, bkc, kd_w, kd_b, y_out);
}

// Round 11
// 324.636 us; speedup vs baseline: 1.2141x; 1.0101x over previous
//
#include <hip/hip_runtime.h>
#include <hip/hip_bf16.h>
#include <cstdint>
#include <cstddef>

// Problem constants
#define NSEQ 4096
#define MDIM 1024
// band: |i-j| < 250 -> row-tile ti needs col-tiles [ti-2, ti+2]
// banded layout (Eband bf16 = exp(logits), attT fp8 x16): row i, col c = j - 128*((i>>7)-2), width 640
// fp8 scaling: attn weights x64, attT x16, y stored x8; MLP kept bf16 for accuracy.
// GEMM operand rule: A = matrix indexing the OUTPUT'S MINOR DIM.
// MFMA: MX-scaled mfma_f32_16x16x128_f8f6f4, unit scales (0x7F=2^0), 2x fp8 rate.
// r7 (BEST, 325.9us): counted-vmcnt pipeline: issue tile t+1's 8 gload_lds,
//   s_waitcnt vmcnt(8) ("memory"-clobbered asm -- r10 showed removing the clobber
//   + sched_barrier fences REGRESSES: VGPR 124->88, compiler schedules less
//   aggressively, k_qkv 57.4->60.6), raw s_barrier, compute, s_barrier.
// r8/r9 lesson: A-from-global LDS bypass stalls (exposed L2 latency per tile,
//   MfmaUtil 15%) regardless of reg-prefetch. REVERTED.
// r11: exact r7 restore (best measured config of every component).
// r4 lesson: 128^2 MLP tile -> grid collapse. MLP = dbuf 64^2 k_gemm64.

typedef __attribute__((ext_vector_type(8))) short short8;
typedef __attribute__((ext_vector_type(4))) float f32x4;
typedef __attribute__((ext_vector_type(2))) long long2v;
typedef __attribute__((ext_vector_type(8))) int int8v;
typedef __attribute__((ext_vector_type(4))) int int4v;

typedef const __attribute__((address_space(1))) void gvoid_t;
typedef __attribute__((address_space(3))) void lvoid_t;

__device__ __forceinline__ unsigned short f2b(float x) {
  union { float f; unsigned int u; } a; a.f = x;
  unsigned int r = (a.u + 0x7fffu + ((a.u >> 16) & 1u)) >> 16;
  return (unsigned short)r;
}
__device__ __forceinline__ float b2f(unsigned short u) {
  union { float f; unsigned int u32; } a; a.u32 = ((unsigned int)u) << 16;
  return a.f;
}
__device__ __forceinline__ unsigned char f2e4(float x) {
  return (unsigned char)(__builtin_amdgcn_cvt_pk_fp8_f32(x, x, 0, false) & 0xff);
}
__device__ __forceinline__ unsigned int f2e4x4(float a, float b, float c, float d) {
  unsigned int lo = __builtin_amdgcn_cvt_pk_fp8_f32(a, b, 0, false);
  return (unsigned int)__builtin_amdgcn_cvt_pk_fp8_f32(c, d, lo, true);
}

__device__ __forceinline__ int8v pack32(const unsigned char* p0,
                                        const unsigned char* p1) {
  int4v lo = *(const int4v*)p0;
  int4v hi = *(const int4v*)p1;
  int8v r;
  r[0] = lo[0]; r[1] = lo[1]; r[2] = lo[2]; r[3] = lo[3];
  r[4] = hi[0]; r[5] = hi[1]; r[6] = hi[2]; r[7] = hi[3];
  return r;
}

// -------- merged cvt: Wq..Wo (x64)->fp8, ka/kb/kc->bf16, x1..x3->fp8, zero sums ----
__global__ __launch_bounds__(256) void k_cvt_all(
    const float* __restrict__ s0, const float* __restrict__ s1,
    const float* __restrict__ s2, const float* __restrict__ s3,
    const float* __restrict__ s4, const float* __restrict__ s5,
    const float* __restrict__ s6,
    const float* __restrict__ xa, const float* __restrict__ xb,
    const float* __restrict__ xc,
    unsigned char* __restrict__ Wf8, unsigned short* __restrict__ Wmlp,
    unsigned char* __restrict__ Xdst, float* __restrict__ sums) {
  int idx = blockIdx.x * 256 + threadIdx.x;  // chunk of 4 floats
  if (idx < 1048576) {  // Wq,Wk,Wv,Wo fp8 x64
    int seg = idx >> 18, local = idx & 262143;
    const float* src = (seg == 0) ? s0 : (seg == 1) ? s1 : (seg == 2) ? s2 : s3;
    float4 v = *(const float4*)(src + (size_t)local * 4);
    *(unsigned int*)(Wf8 + (size_t)idx * 4) =
        f2e4x4(v.x * 64.f, v.y * 64.f, v.z * 64.f, v.w * 64.f);
  } else if (idx < 1458176) {  // ka,kb,kc bf16
    int i2 = idx - 1048576;
    const float* src; int local;
    if (i2 < 262144) { src = s4; local = i2; }
    else if (i2 < 393216) { src = s5; local = i2 - 262144; }
    else { src = s6; local = i2 - 393216; }
    float4 v = *(const float4*)(src + (size_t)local * 4);
    ushort4 o; o.x = f2b(v.x); o.y = f2b(v.y); o.z = f2b(v.z); o.w = f2b(v.w);
    *(ushort4*)(Wmlp + (size_t)i2 * 4) = o;
  } else if (idx < 4603904) {  // x1..x3 fp8
    int i2 = idx - 1458176;   // 0 .. 3*2^20-1
    int seg = i2 >> 20, local = i2 & 1048575;
    const float* src = (seg == 0) ? xa : (seg == 1) ? xb : xc;
    float4 v = *(const float4*)(src + (size_t)local * 4);
    *(unsigned int*)(Xdst + (size_t)i2 * 4) = f2e4x4(v.x, v.y, v.z, v.w);
  } else {  // zero softmax denominators (12288 floats)
    int i3 = idx - 4603904;   // 0..3071
    *(float4*)(sums + (size_t)i3 * 4) = make_float4(0.f, 0.f, 0.f, 0.f);
  }
}

// -------- fp8 GEMM core (templated), counted-vmcnt pipeline, direct-store --------
// BK=128, global_load_lds 16B staging; LDS row=128B=8 slots; slot s holds chunk (s-r)&7.
// One mfma_scale_f32_16x16x128_f8f6f4 per (m,n) per K-tile, unit scales.
// OKIND: 1=bf16(8B, DO_EXP optional), 2=fp8(dword).
// MODE 3: QKV. by<8: Q; 8..15: K; >=16: VT. MODE 1: logits+rowsums.
// MODE 2: y=attT@V (K window). MODE 0: Wo.
template <int MODE, int OKIND, int DO_EXP>
__device__ __forceinline__ void gemm_core(
    const unsigned char* __restrict__ A, int lda,
    const unsigned char* __restrict__ B, int ldb,
    void* __restrict__ Cout, void* __restrict__ Cout2, int ldc,
    int K, float alpha,
    const unsigned char* __restrict__ A1, const unsigned char* __restrict__ A2,
    float* __restrict__ sums_out, unsigned char* __restrict__ smem) {
  int bx = blockIdx.x, by = blockIdx.y;
  const unsigned char* Ab;
  const unsigned char* Bb;
  void* Cdst = Cout;
  int k0 = 0, k1 = K, b_koff = 0;
  int ldce = ldc;
  int rbase, cbase;
  int ldae = lda, ldbe = ldb;
  if constexpr (MODE == 0) {
    Ab = A + (size_t)by * 128 * lda;      // Wo rows
    Bb = B + (size_t)bx * 128 * ldb;      // y rows
    rbase = bx * 128; cbase = by * 128;
  } else if constexpr (MODE == 3) {
    if (by < 16) {
      Ab = A + (size_t)by * 128 * lda;    // Wq|Wk contiguous rows
      Bb = B + (size_t)bx * 128 * ldb;    // X rows
      if (by >= 8) Cdst = Cout2;
      rbase = bx * 128; cbase = (by & 7) * 128;
    } else {
      Ab = B + (size_t)bx * 128 * ldb;                 // X rows (qc = x)
      Bb = A1 + (size_t)(by - 16) * 128 * 1024;        // Wv rows (qr = wv)
      Cdst = (void*)const_cast<unsigned char*>(A2);    // VT [1024,12288]
      rbase = (by - 16) * 128; cbase = bx * 128;
      ldce = 3 * NSEQ;
    }
  } else if constexpr (MODE == 1) {
    int s = bx >> 5, ti = bx & 31;
    int bt = ti + by - 2;                        // validity checked by caller
    Ab = A + (size_t)(s * 32 + bt) * 128 * lda;  // K rows (qc = band col)
    Bb = B + (size_t)bx * 128 * ldb;             // Q rows (qr = i)
    rbase = bx * 128; cbase = by * 128;          // ldce = 640
  } else {  // MODE == 2
    int s = bx >> 5, ti = bx & 31;
    Ab = A + (size_t)by * 128 * lda + s * NSEQ;   // VT rows (qc = v), col offset s*4096
    const unsigned char* Bbase = (s == 0) ? B : ((s == 1) ? A1 : A2);
    Bb = Bbase + (size_t)ti * 128 * 640;          // attT banded rows (qr = i)
    ldbe = 640;
    int lo = ti - 2; if (lo < 0) lo = 0;
    int hi = ti + 3; if (hi > 32) hi = 32;
    k0 = lo * 128; k1 = hi * 128;
    b_koff = (ti - 2) * 128;
    rbase = bx * 128; cbase = by * 128;
  }

  const int t = threadIdx.x;
  const int l = t & 63;
  const int w = t >> 6;
  const int fr = l & 15;
  const int quad = l >> 4;
  const int wm = (w >> 1) * 64;
  const int wn = (w & 1) * 64;
  const int fq4 = quad * 4;

  // staging: 4 insts per matrix per wave; inst j covers rows w*32+j*8 .. +7
  int srow[4], scg[4], sloff[4];
#pragma unroll
  for (int j = 0; j < 4; j++) {
    srow[j] = w * 32 + j * 8 + (l >> 3);
    scg[j] = ((l & 7) - srow[j]) & 7;       // global chunk for LDS slot l&7
    sloff[j] = (w * 32 + j * 8) * 128 + l * 16;
  }

  f32x4 acc[4][4];
#pragma unroll
  for (int m = 0; m < 4; m++)
#pragma unroll
    for (int n = 0; n < 4; n++) acc[m][n] = (f32x4){0.f, 0.f, 0.f, 0.f};

  const int c0 = quad * 2;   // first 16B chunk of this lane's K-block
  const int nt = (k1 - k0) >> 7;

  // prologue: issue tile 0 -> buf 0 (8 loads/wave, left in flight)
  {
    int kk = k0, kb = kk - b_koff;
#pragma unroll
    for (int j = 0; j < 4; j++)
      __builtin_amdgcn_global_load_lds(
          (gvoid_t*)(Ab + (size_t)srow[j] * ldae + kk + scg[j] * 16),
          (lvoid_t*)(smem + sloff[j]), 16, 0, 0);
#pragma unroll
    for (int j = 0; j < 4; j++)
      __builtin_amdgcn_global_load_lds(
          (gvoid_t*)(Bb + (size_t)srow[j] * ldbe + kb + scg[j] * 16),
          (lvoid_t*)(smem + 16384 + sloff[j]), 16, 0, 0);
  }

  for (int tt = 0; tt < nt; tt++) {
    if (tt + 1 < nt) {
      // issue tile t+1's 8 loads into the other buffer (WAR-safe: prior iter's
      // trailing barrier guaranteed all waves retired their reads of it)
      int kk = k0 + (tt + 1) * 128, kb = kk - b_koff;
      unsigned char* Asn = smem + ((tt + 1) & 1) * 32768;
#pragma unroll
      for (int j = 0; j < 4; j++)
        __builtin_amdgcn_global_load_lds(
            (gvoid_t*)(Ab + (size_t)srow[j] * ldae + kk + scg[j] * 16),
            (lvoid_t*)(Asn + sloff[j]), 16, 0, 0);
#pragma unroll
      for (int j = 0; j < 4; j++)
        __builtin_amdgcn_global_load_lds(
            (gvoid_t*)(Bb + (size_t)srow[j] * ldbe + kb + scg[j] * 16),
            (lvoid_t*)(Asn + 16384 + sloff[j]), 16, 0, 0);
      __builtin_amdgcn_sched_barrier(0);
      // wait only the 8 OLDEST (tile t); tile t+1's 8 stay in flight across barrier
      asm volatile("s_waitcnt vmcnt(8)" ::: "memory");
    } else {
      asm volatile("s_waitcnt vmcnt(0)" ::: "memory");
    }
    asm volatile("s_barrier" ::: "memory");   // tile t fully in LDS, all waves

    const unsigned char* Asc = smem + (tt & 1) * 32768;
    const unsigned char* Bsc = Asc + 16384;
    int8v a8[4], b8[4];
#pragma unroll
    for (int m = 0; m < 4; m++) {
      int r = wm + m * 16 + fr;
      int s0i = (c0 + r) & 7, s1i = (s0i + 1) & 7;
      a8[m] = pack32(Asc + r * 128 + s0i * 16, Asc + r * 128 + s1i * 16);
    }
#pragma unroll
    for (int n = 0; n < 4; n++) {
      int r = wn + n * 16 + fr;
      int s0i = (c0 + r) & 7, s1i = (s0i + 1) & 7;
      b8[n] = pack32(Bsc + r * 128 + s0i * 16, Bsc + r * 128 + s1i * 16);
    }
#pragma unroll
    for (int m = 0; m < 4; m++)
#pragma unroll
      for (int n = 0; n < 4; n++)
        acc[m][n] = __builtin_amdgcn_mfma_scale_f32_16x16x128_f8f6f4(
            a8[m], b8[n], acc[m][n], 0, 0, 0, 0x7F7F7F7F, 0, 0x7F7F7F7F);
    asm volatile("s_barrier" ::: "memory");   // all reads of buf[tt&1] retired
  }

  // direct-store epilogue; MODE 1 also accumulates the in-band row-sum of exp
  float rowsum[4] = {0.f, 0.f, 0.f, 0.f};
  const int jb = ((bx & 31) - 2) * 128;   // used only when MODE==1
#pragma unroll
  for (int m = 0; m < 4; m++) {
#pragma unroll
    for (int n = 0; n < 4; n++) {
      int oc = cbase + wm + m * 16 + fq4;
      int orow = rbase + wn + n * 16 + fr;
      float v0 = acc[m][n][0] * alpha, v1 = acc[m][n][1] * alpha;
      float v2 = acc[m][n][2] * alpha, v3 = acc[m][n][3] * alpha;
      if constexpr (OKIND == 1) {
        if constexpr (DO_EXP) {
          v0 = __expf(v0); v1 = __expf(v1); v2 = __expf(v2); v3 = __expf(v3);
          if constexpr (MODE == 1) {
            int d0 = (orow & 4095) - (jb + oc);   // i - j for element 0
            rowsum[n] += ((unsigned)(d0 + 249) < 499u ? v0 : 0.f)
                       + ((unsigned)(d0 + 248) < 499u ? v1 : 0.f)
                       + ((unsigned)(d0 + 247) < 499u ? v2 : 0.f)
                       + ((unsigned)(d0 + 246) < 499u ? v3 : 0.f);
          }
        }
        ushort4 o; o.x = f2b(v0); o.y = f2b(v1); o.z = f2b(v2); o.w = f2b(v3);
        *(uint2*)((unsigned short*)Cdst + (size_t)orow * ldce + oc) = *(uint2*)&o;
      } else {
        *(unsigned int*)((unsigned char*)Cdst + (size_t)orow * ldce + oc) =
            f2e4x4(v0, v1, v2, v3);
      }
    }
  }
  if constexpr (MODE == 1 && DO_EXP) {
    // lanes {fr, fr+16, fr+32, fr+48} hold the same rows; reduce across quads
#pragma unroll
    for (int n = 0; n < 4; n++) {
      float sv = rowsum[n];
      sv += __shfl_xor(sv, 16);
      sv += __shfl_xor(sv, 32);
      if (quad == 0) {
        int orow = rbase + wn + n * 16 + fr;
        atomicAdd(sums_out + orow, sv);
      }
    }
  }
}

// QKV fp8: counted-vmcnt pipelined
__global__ __launch_bounds__(256) void k_qkv(
    const unsigned char* __restrict__ A, const unsigned char* __restrict__ B,
    void* __restrict__ Cout, void* __restrict__ Cout2, float alpha,
    const unsigned char* __restrict__ A1, const unsigned char* __restrict__ A2) {
  __shared__ unsigned char smem[4 * 128 * 128];
  gemm_core<3, 2, 0>(A, 1024, B, 1024, Cout, Cout2, 1024, 1024, alpha,
                     A1, A2, nullptr, smem);
}

// logits -> Eband (exp) + fused band row-sums
__global__ __launch_bounds__(256) void k_logits(
    const unsigned char* __restrict__ A, const unsigned char* __restrict__ B,
    void* __restrict__ Cout, float alpha, float* __restrict__ sums) {
  int ti = blockIdx.x & 31;
  int bt = ti + (int)blockIdx.y - 2;
  if (bt < 0 || bt >= 32) return;   // whole-block, before any barrier
  __shared__ unsigned char smem[4 * 128 * 128];
  gemm_core<1, 1, 1>(A, 1024, B, 1024, Cout, nullptr, 640, 1024, alpha,
                     nullptr, nullptr, sums, smem);
}

// y = attT @ V (banded K window)
__global__ __launch_bounds__(256) void k_av(
    const unsigned char* __restrict__ A, const unsigned char* __restrict__ B,
    void* __restrict__ Cout, float alpha,
    const unsigned char* __restrict__ A1, const unsigned char* __restrict__ A2) {
  __shared__ unsigned char smem[4 * 128 * 128];
  gemm_core<2, 2, 0>(A, 3 * NSEQ, B, 640, Cout, nullptr, 1024, NSEQ, alpha,
                     A1, A2, nullptr, smem);
}

// yo = y @ Wo^T (bf16 out, no exp)
__global__ __launch_bounds__(256) void k_wo(
    const unsigned char* __restrict__ A, const unsigned char* __restrict__ B,
    void* __restrict__ Cout, float alpha) {
  __shared__ unsigned char smem[4 * 128 * 128];
  gemm_core<0, 1, 0>(A, 1024, B, 1024, Cout, nullptr, 1024, 1024, alpha,
                     nullptr, nullptr, nullptr, smem);
}

// -------- small bf16 GEMM: 64x64 tile, BK=64, 2-phase dbuf --------
// A = weight (qc dim), B = activation (qr dim).
__global__ __launch_bounds__(256) void k_gemm64(
    const unsigned short* __restrict__ A, int lda,
    const unsigned short* __restrict__ B, int ldb,
    void* __restrict__ Cout, int ldc, int K,
    const float* __restrict__ bias, int relu, int out_bf16) {
  __shared__ unsigned short smem[4 * 64 * 64];  // 32 KB: 2 bufs x (A | B)
  int bx = blockIdx.x, by = blockIdx.y;
  const unsigned short* Ab = A + (size_t)by * 64 * lda;   // weight rows
  const unsigned short* Bb = B + (size_t)bx * 64 * ldb;   // activation rows
  int rbase = bx * 64, cbase = by * 64;

  const int t = threadIdx.x;
  const int l = t & 63;
  const int w = t >> 6;
  const int fr = l & 15;
  const int quad = l >> 4;
  const int wm = (w & 1) * 32;
  const int wn = (w >> 1) * 32;
  const int fq4 = quad * 4;

  int srow[2], scg[2], sloff[2];
#pragma unroll
  for (int j = 0; j < 2; j++) {
    srow[j] = w * 16 + j * 8 + (l >> 3);
    scg[j] = ((l & 7) - srow[j]) & 7;
    sloff[j] = (w * 16 + j * 8) * 64 + l * 8;
  }

  f32x4 acc[2][2];
#pragma unroll
  for (int m = 0; m < 2; m++)
#pragma unroll
    for (int n = 0; n < 2; n++) acc[m][n] = (f32x4){0.f, 0.f, 0.f, 0.f};

  const int nt = K >> 6;

  // prologue: stage tile 0 -> buf 0
#pragma unroll
  for (int j = 0; j < 2; j++)
    __builtin_amdgcn_global_load_lds(
        (gvoid_t*)(Ab + (size_t)srow[j] * lda + scg[j] * 8),
        (lvoid_t*)(smem + sloff[j]), 16, 0, 0);
#pragma unroll
  for (int j = 0; j < 2; j++)
    __builtin_amdgcn_global_load_lds(
        (gvoid_t*)(Bb + (size_t)srow[j] * ldb + scg[j] * 8),
        (lvoid_t*)(smem + 4096 + sloff[j]), 16, 0, 0);

  for (int tt = 0; tt < nt; tt++) {
    __syncthreads();   // buf[tt&1] ready; all waves done reading buf[(tt+1)&1]
    if (tt + 1 < nt) {
      int kk = (tt + 1) * 64;
      unsigned short* Asn = smem + ((tt + 1) & 1) * 8192;
#pragma unroll
      for (int j = 0; j < 2; j++)
        __builtin_amdgcn_global_load_lds(
            (gvoid_t*)(Ab + (size_t)srow[j] * lda + kk + scg[j] * 8),
            (lvoid_t*)(Asn + sloff[j]), 16, 0, 0);
#pragma unroll
      for (int j = 0; j < 2; j++)
        __builtin_amdgcn_global_load_lds(
            (gvoid_t*)(Bb + (size_t)srow[j] * ldb + kk + scg[j] * 8),
            (lvoid_t*)(Asn + 4096 + sloff[j]), 16, 0, 0);
    }
    const unsigned short* Asc = smem + (tt & 1) * 8192;
    const unsigned short* Bsc = Asc + 4096;
#pragma unroll
    for (int s = 0; s < 2; s++) {
      short8 af[2], bf[2];
#pragma unroll
      for (int m = 0; m < 2; m++) {
        int r = wm + m * 16 + fr;
        int slot = (s * 4 + quad + r) & 7;
        af[m] = *(const short8*)(Asc + r * 64 + slot * 8);
      }
#pragma unroll
      for (int n = 0; n < 2; n++) {
        int r = wn + n * 16 + fr;
        int slot = (s * 4 + quad + r) & 7;
        bf[n] = *(const short8*)(Bsc + r * 64 + slot * 8);
      }
#pragma unroll
      for (int m = 0; m < 2; m++)
#pragma unroll
        for (int n = 0; n < 2; n++)
          acc[m][n] = __builtin_amdgcn_mfma_f32_16x16x32_bf16(af[m], bf[n], acc[m][n], 0, 0, 0);
    }
  }

#pragma unroll
  for (int m = 0; m < 2; m++) {
#pragma unroll
    for (int n = 0; n < 2; n++) {
      int oc = cbase + wm + m * 16 + fq4;
      int orow = rbase + wn + n * 16 + fr;
      float4 bv = bias ? *(const float4*)(bias + oc) : make_float4(0.f, 0.f, 0.f, 0.f);
      float v0 = acc[m][n][0] + bv.x, v1 = acc[m][n][1] + bv.y;
      float v2 = acc[m][n][2] + bv.z, v3 = acc[m][n][3] + bv.w;
      if (relu) {
        v0 = fmaxf(v0, 0.f); v1 = fmaxf(v1, 0.f);
        v2 = fmaxf(v2, 0.f); v3 = fmaxf(v3, 0.f);
      }
      if (out_bf16) {
        ushort4 o; o.x = f2b(v0); o.y = f2b(v1); o.z = f2b(v2); o.w = f2b(v3);
        *(uint2*)((unsigned short*)Cout + (size_t)orow * ldc + oc) = *(uint2*)&o;
      } else {
        *(float4*)((float*)Cout + (size_t)orow * ldc + oc) = make_float4(v0, v1, v2, v3);
      }
    }
  }
}

// -------- build banded attT (fp8 x16): attT_s[i][j - 128*((i>>7)-2)] = 16*att[j][i] --------
__global__ __launch_bounds__(256) void k_build_attT(const unsigned short* __restrict__ Eband,
                                                    const float* __restrict__ sums,
                                                    unsigned char* __restrict__ t0,
                                                    unsigned char* __restrict__ t1,
                                                    unsigned char* __restrict__ t2) {
  int byy = blockIdx.y;
  int s = byy >> 5, ti = byy & 31;       // i tile (attT rows), local
  int tj = ti + (int)blockIdx.x - 2;     // j tile
  if (tj < 0 || tj >= 32) return;
  unsigned char* dst = (s == 0) ? t0 : ((s == 1) ? t1 : t2);
  __shared__ unsigned char T[128][132];  // T[i_loc][j_loc]
  int t = threadIdx.x;
  int c0 = (ti - tj + 2) * 128;  // Eband col base for rows j reading i-tile ti
  int colg = (t & 31) * 4;       // i_loc
  for (int jj = t >> 5; jj < 128; jj += 8) {
    int jg = s * NSEQ + tj * 128 + jj;
    float inv = 16.f / sums[jg];
    ushort4 v = *(const ushort4*)&Eband[(size_t)jg * 640 + c0 + colg];
    float vv[4] = {b2f(v.x), b2f(v.y), b2f(v.z), b2f(v.w)};
#pragma unroll
    for (int q = 0; q < 4; q++) {
      int i = ti * 128 + colg + q;
      int d = i - (tj * 128 + jj);
      float a = (d < 250 && d > -250) ? vv[q] * inv : 0.f;
      T[colg + q][jj] = f2e4(a);
    }
  }
  __syncthreads();
  int jb0 = (tj - ti + 2) * 128;  // banded col base in attT rows of tile ti
  for (int ii = t >> 5; ii < 128; ii += 8) {
    size_t o = (size_t)(ti * 128 + ii) * 640 + jb0 + colg;
    *(unsigned int*)(dst + o) = *(const unsigned int*)&T[ii][colg];
  }
}

// -------- write full fp32 att (stream 0 / x1), zeros outside band --------
__global__ __launch_bounds__(256) void k_write_att(const unsigned short* __restrict__ Eband,
                                                   const float* __restrict__ sums,
                                                   float* __restrict__ att) {
  int i = blockIdx.x;
  int ti = i >> 7, cbase = (ti - 2) * 128;
  int jlo = i - 249; if (jlo < 0) jlo = 0;
  int jhi = i + 249; if (jhi > NSEQ - 1) jhi = NSEQ - 1;
  float inv = 1.f / sums[i];
  const unsigned short* L = Eband + (size_t)i * 640;
  float* arow = att + (size_t)i * NSEQ;
  for (int j0 = threadIdx.x * 4; j0 < NSEQ; j0 += 1024) {
    float ov[4];
#pragma unroll
    for (int q = 0; q < 4; q++) {
      int j = j0 + q;
      ov[q] = (j >= jlo && j <= jhi) ? b2f(L[j - cbase]) * inv : 0.f;
    }
    *(float4*)(arow + j0) = make_float4(ov[0], ov[1], ov[2], ov[3]);
  }
}

// -------- residual + LayerNorm (ddof=1, eps on std) for 3 streams, sum -> bf16 --------
__global__ __launch_bounds__(256) void k_ln3(const unsigned short* __restrict__ yo,
                                             const float* __restrict__ x1,
                                             const float* __restrict__ x2,
                                             const float* __restrict__ x3,
                                             const float* __restrict__ g,
                                             const float* __restrict__ b,
                                             unsigned short* __restrict__ ysum_b) {
  int i = blockIdx.x, t = threadIdx.x;
  int w = t >> 6, lane = t & 63;
  __shared__ float red[8];
  const float* xs[3] = {x1, x2, x3};
  float4 gg = *(const float4*)(g + t * 4);
  float4 bb = *(const float4*)(b + t * 4);
  float acc[4] = {0.f, 0.f, 0.f, 0.f};
  for (int s = 0; s < 3; s++) {
    ushort4 yv = *(const ushort4*)(yo + ((size_t)(s * NSEQ + i)) * MDIM + t * 4);
    float4 xx = *(const float4*)(xs[s] + (size_t)i * MDIM + t * 4);
    float v[4] = {b2f(yv.x) + xx.x, b2f(yv.y) + xx.y, b2f(yv.z) + xx.z, b2f(yv.w) + xx.w};
    float s1 = v[0] + v[1] + v[2] + v[3];
    float s2 = v[0]*v[0] + v[1]*v[1] + v[2]*v[2] + v[3]*v[3];
    for (int off = 32; off; off >>= 1) { s1 += __shfl_xor(s1, off); s2 += __shfl_xor(s2, off); }
    __syncthreads();
    if (lane == 0) { red[w] = s1; red[4 + w] = s2; }
    __syncthreads();
    float S1 = red[0] + red[1] + red[2] + red[3];
    float S2 = red[4] + red[5] + red[6] + red[7];
    float mean = S1 * (1.f / 1024.f);
    float var = (S2 - S1 * mean) * (1.f / 1023.f);
    float rstd = 1.f / (sqrtf(var) + 1e-6f);
    acc[0] += gg.x * (v[0] - mean) * rstd + bb.x;
    acc[1] += gg.y * (v[1] - mean) * rstd + bb.y;
    acc[2] += gg.z * (v[2] - mean) * rstd + bb.z;
    acc[3] += gg.w * (v[3] - mean) * rstd + bb.w;
  }
  ushort4 o;
  o.x = f2b(acc[0]); o.y = f2b(acc[1]); o.z = f2b(acc[2]); o.w = f2b(acc[3]);
  *(ushort4*)(ysum_b + (size_t)i * MDIM + t * 4) = o;
}

// -------- final: LN(128, gkc/bkc) -> dot(kd_w) + kd_b -> sigmoid --------
__global__ __launch_bounds__(128) void k_final(const float* __restrict__ h3,
                                               const float* __restrict__ g,
                                               const float* __restrict__ b,
                                               const float* __restrict__ kdw,
                                               const float* __restrict__ kdb,
                                               float* __restrict__ yout) {
  int i = blockIdx.x, t = threadIdx.x;
  float v = h3[(size_t)i * 128 + t];
  float s1 = v, s2 = v * v;
  for (int off = 32; off; off >>= 1) { s1 += __shfl_xor(s1, off); s2 += __shfl_xor(s2, off); }
  __shared__ float red[4];
  int w = t >> 6, lane = t & 63;
  if (lane == 0) { red[w] = s1; red[2 + w] = s2; }
  __syncthreads();
  float S1 = red[0] + red[1], S2 = red[2] + red[3];
  float mean = S1 * (1.f / 128.f);
  float var = (S2 - S1 * mean) * (1.f / 127.f);
  float rstd = 1.f / (sqrtf(var) + 1e-6f);
  float ln = g[t] * (v - mean) * rstd + b[t];
  float p = ln * kdw[t];
  for (int off = 32; off; off >>= 1) p += __shfl_xor(p, off);
  __syncthreads();
  if (lane == 0) red[w] = p;
  __syncthreads();
  if (t == 0) {
    float z = red[0] + red[1] + kdb[0];
    yout[i] = 1.f / (1.f + __expf(-z));
  }
}

extern "C" void kernel_launch(void* const* d_in, const int* in_sizes, int n_in,
                              void* d_out, int out_size, void* d_ws, size_t ws_size,
                              hipStream_t stream) {
  const float* x1 = (const float*)d_in[0];
  const float* x2 = (const float*)d_in[1];
  const float* x3 = (const float*)d_in[2];
  const float* Wq = (const float*)d_in[3];
  const float* Wk = (const float*)d_in[4];
  const float* Wv = (const float*)d_in[5];
  const float* Wo = (const float*)d_in[6];
  const float* ka_w = (const float*)d_in[7];
  const float* ka_b = (const float*)d_in[8];
  const float* kb_w = (const float*)d_in[9];
  const float* kb_b = (const float*)d_in[10];
  const float* kc_w = (const float*)d_in[11];
  const float* kc_b = (const float*)d_in[12];
  const float* kd_w = (const float*)d_in[13];
  const float* kd_b = (const float*)d_in[14];
  const float* g13 = (const float*)d_in[15];
  const float* b13 = (const float*)d_in[16];
  const float* gkc = (const float*)d_in[17];
  const float* bkc = (const float*)d_in[18];

  float* y_out = (float*)d_out;
  float* att_out = y_out + NSEQ;  // [4096,4096] fp32

  char* ws = (char*)d_ws;
  size_t off = 0;
  auto alloc = [&](size_t bytes) -> void* {
    void* p = ws + off;
    off += (bytes + 255) & ~(size_t)255;
    return p;
  };
  const size_t NM = (size_t)3 * NSEQ * MDIM;  // 12.6M elems
  // fp8 attention weights, contiguous: Wq|Wk|Wv|Wo (x64 scaled)
  unsigned char* Wf = (unsigned char*)alloc(4 * 1048576);
  // bf16 MLP weights, contiguous: ka|kb|kc
  unsigned short* Wmlp = (unsigned short*)alloc((1048576 + 524288 + 65536) * 2);
  unsigned char* Xf = (unsigned char*)alloc(NM);      // later: yb fp8, then h1b bf16
  unsigned char* Qf = (unsigned char*)alloc(NM);      // yo bf16 spans Qf+Kf; later h2b
  unsigned char* Kf = (unsigned char*)alloc(NM);
  unsigned char* VTf = (unsigned char*)alloc(NM);     // later: ysum_b bf16 (8MB)
  unsigned short* Eband = (unsigned short*)alloc((size_t)3 * NSEQ * 640 * 2);
  float* sums = (float*)alloc((size_t)3 * NSEQ * 4);
  unsigned char* aT0 = (unsigned char*)alloc((size_t)NSEQ * 640);  // later: h3 f32
  unsigned char* aT1 = (unsigned char*)alloc((size_t)NSEQ * 640);
  unsigned char* aT2 = (unsigned char*)alloc((size_t)NSEQ * 640);
  // weight sub-pointers
  unsigned char* Wv_f = Wf + 2097152;
  unsigned char* Wo_f = Wf + 3145728;
  unsigned short* ka_b16 = Wmlp;
  unsigned short* kb_b16 = Wmlp + 1048576;
  unsigned short* kc_b16 = Wmlp + 1572864;
  // aliases (lifetimes disjoint)
  unsigned char* yb = Xf;                       // fp8 [12288,1024] = 8*y
  unsigned short* yo = (unsigned short*)Qf;     // bf16 [12288,1024] spans Qf..Kf
  unsigned short* ysum_b = (unsigned short*)VTf;// bf16 [4096,1024]
  unsigned short* h1b = (unsigned short*)Xf;    // bf16 [4096,1024]
  unsigned short* h2b = (unsigned short*)Qf;    // bf16 [4096,512]
  float* h3 = (float*)aT0;                      // f32 [4096,128]

  // all conversions + sums zero-init in one dispatch
  k_cvt_all<<<17996, 256, 0, stream>>>(Wq, Wk, Wv, Wo, ka_w, kb_w, kc_w,
                                       x1, x2, x3, Wf, Wmlp, Xf, sums);

  // merged Q+K+VT fp8: Q/K: A=Wq|Wk, B=X; VT: A=X, B=Wv
  k_qkv<<<dim3(96, 24), 256, 0, stream>>>(Wf, Xf, Qf, Kf, 1.f / 64.f, Wv_f, VTf);
  // banded logits -> E = exp(0.06 * Q.K) bf16 [12288,640] + fused band row-sums
  k_logits<<<dim3(96, 5), 256, 0, stream>>>(Kf, Qf, Eband, 0.06f, sums);
  k_build_attT<<<dim3(5, 96), 256, 0, stream>>>(Eband, sums, aT0, aT1, aT2);
  // yb = 8*y: A=VT (v minor), B=attT banded; (16att)@V * 0.5, fp8 out
  k_av<<<dim3(96, 8), 256, 0, stream>>>(VTf, aT0, yb, 0.5f, aT1, aT2);
  k_write_att<<<4096, 256, 0, stream>>>(Eband, sums, att_out);
  // yo = y @ Wo^T (bf16 out): A=Wo, B=y; (8y)@(64Wo) * 1/512
  k_wo<<<dim3(96, 8), 256, 0, stream>>>(Wo_f, yb, yo, 1.f / 512.f);
  // residual + LN + 3-stream sum -> bf16
  k_ln3<<<4096, 256, 0, stream>>>(yo, x1, x2, x3, g13, b13, ysum_b);

  // MLP head (bf16, 64x64 tiles dbuf, A=weight)
  k_gemm64<<<dim3(64, 16), 256, 0, stream>>>(ka_b16, 1024, ysum_b, 1024, h1b, 1024,
                                             1024, ka_b, 0, 1);
  k_gemm64<<<dim3(64, 8), 256, 0, stream>>>(kb_b16, 1024, h1b, 1024, h2b, 512,
                                            1024, kb_b, 0, 1);
  k_gemm64<<<dim3(64, 2), 256, 0, stream>>>(kc_b16, 512, h2b, 512, h3, 128,
                                            512, kc_b, 1, 0);
  k_final<<<4096, 128, 0, stream>>>(h3, gkc, bkc, kd_w, kd_b, y_out);
}

// Round 12
// 322.910 us; speedup vs baseline: 1.2206x; 1.0053x over previous
//
#include <hip/hip_runtime.h>
#include <hip/hip_bf16.h>
#include <cstdint>
#include <cstddef>

// Problem constants
#define NSEQ 4096
#define MDIM 1024
// band: |i-j| < 250 -> row-tile ti needs col-tiles [ti-2, ti+2]
// banded layout (Eband bf16 = exp(logits), attT fp8 x16): row i, col c = j - 128*((i>>7)-2), width 640
// fp8 scaling: attn weights x64, attT x16, y stored x8; MLP kept bf16 for accuracy.
// GEMM operand rule: A = matrix indexing the OUTPUT'S MINOR DIM.
// MFMA: MX-scaled mfma_f32_16x16x128_f8f6f4, unit scales (0x7F=2^0), 2x fp8 rate.
// r11 analysis: r2 (single-buf) 58.4 ~= r7 (dbuf counted-vmcnt) 57.4 -> per-phase
//   load-wait L dominates and 1-phase lead can't hide it. r12: BK=256 core
//   (gemm_core256) for K=1024 GEMMs: HALF the phases, 2x MFMA per phase, LDS
//   still 64KB single-buffer (A 32K + B 32K) -> occupancy unchanged (2 blocks/CU).
//   Accumulation order unchanged (ascending 128-K chunks) -> bit-identical.
//   k_av keeps r7 core (banded K-window not 256-aligned).
// r12 also merges k_build_attT + k_write_att into k_attw (one dispatch, overlap).
// r8/r9 lesson: per-lane A-from-global stalls (compiler-tracked waits). REVERTED.
// r4 lesson: 128^2 MLP tile -> grid collapse. MLP = dbuf 64^2 k_gemm64.

typedef __attribute__((ext_vector_type(8))) short short8;
typedef __attribute__((ext_vector_type(4))) float f32x4;
typedef __attribute__((ext_vector_type(2))) long long2v;
typedef __attribute__((ext_vector_type(8))) int int8v;
typedef __attribute__((ext_vector_type(4))) int int4v;

typedef const __attribute__((address_space(1))) void gvoid_t;
typedef __attribute__((address_space(3))) void lvoid_t;

__device__ __forceinline__ unsigned short f2b(float x) {
  union { float f; unsigned int u; } a; a.f = x;
  unsigned int r = (a.u + 0x7fffu + ((a.u >> 16) & 1u)) >> 16;
  return (unsigned short)r;
}
__device__ __forceinline__ float b2f(unsigned short u) {
  union { float f; unsigned int u32; } a; a.u32 = ((unsigned int)u) << 16;
  return a.f;
}
__device__ __forceinline__ unsigned char f2e4(float x) {
  return (unsigned char)(__builtin_amdgcn_cvt_pk_fp8_f32(x, x, 0, false) & 0xff);
}
__device__ __forceinline__ unsigned int f2e4x4(float a, float b, float c, float d) {
  unsigned int lo = __builtin_amdgcn_cvt_pk_fp8_f32(a, b, 0, false);
  return (unsigned int)__builtin_amdgcn_cvt_pk_fp8_f32(c, d, lo, true);
}

__device__ __forceinline__ int8v pack32(const unsigned char* p0,
                                        const unsigned char* p1) {
  int4v lo = *(const int4v*)p0;
  int4v hi = *(const int4v*)p1;
  int8v r;
  r[0] = lo[0]; r[1] = lo[1]; r[2] = lo[2]; r[3] = lo[3];
  r[4] = hi[0]; r[5] = hi[1]; r[6] = hi[2]; r[7] = hi[3];
  return r;
}

// -------- merged cvt: Wq..Wo (x64)->fp8, ka/kb/kc->bf16, x1..x3->fp8, zero sums ----
__global__ __launch_bounds__(256) void k_cvt_all(
    const float* __restrict__ s0, const float* __restrict__ s1,
    const float* __restrict__ s2, const float* __restrict__ s3,
    const float* __restrict__ s4, const float* __restrict__ s5,
    const float* __restrict__ s6,
    const float* __restrict__ xa, const float* __restrict__ xb,
    const float* __restrict__ xc,
    unsigned char* __restrict__ Wf8, unsigned short* __restrict__ Wmlp,
    unsigned char* __restrict__ Xdst, float* __restrict__ sums) {
  int idx = blockIdx.x * 256 + threadIdx.x;  // chunk of 4 floats
  if (idx < 1048576) {  // Wq,Wk,Wv,Wo fp8 x64
    int seg = idx >> 18, local = idx & 262143;
    const float* src = (seg == 0) ? s0 : (seg == 1) ? s1 : (seg == 2) ? s2 : s3;
    float4 v = *(const float4*)(src + (size_t)local * 4);
    *(unsigned int*)(Wf8 + (size_t)idx * 4) =
        f2e4x4(v.x * 64.f, v.y * 64.f, v.z * 64.f, v.w * 64.f);
  } else if (idx < 1458176) {  // ka,kb,kc bf16
    int i2 = idx - 1048576;
    const float* src; int local;
    if (i2 < 262144) { src = s4; local = i2; }
    else if (i2 < 393216) { src = s5; local = i2 - 262144; }
    else { src = s6; local = i2 - 393216; }
    float4 v = *(const float4*)(src + (size_t)local * 4);
    ushort4 o; o.x = f2b(v.x); o.y = f2b(v.y); o.z = f2b(v.z); o.w = f2b(v.w);
    *(ushort4*)(Wmlp + (size_t)i2 * 4) = o;
  } else if (idx < 4603904) {  // x1..x3 fp8
    int i2 = idx - 1458176;   // 0 .. 3*2^20-1
    int seg = i2 >> 20, local = i2 & 1048575;
    const float* src = (seg == 0) ? xa : (seg == 1) ? xb : xc;
    float4 v = *(const float4*)(src + (size_t)local * 4);
    *(unsigned int*)(Xdst + (size_t)i2 * 4) = f2e4x4(v.x, v.y, v.z, v.w);
  } else {  // zero softmax denominators (12288 floats)
    int i3 = idx - 4603904;   // 0..3071
    *(float4*)(sums + (size_t)i3 * 4) = make_float4(0.f, 0.f, 0.f, 0.f);
  }
}

// -------- fp8 GEMM core, BK=256, single-buffer 2-barrier (r2 pattern) --------
// A tile 128x256 (32KB) + B tile 128x256 (32KB); LDS row = 256B = 16 slots of 16B;
// slot s of row r holds global chunk (s-r)&15 (rotation swizzle). Per phase:
// 16 gload_lds/wave, 2 sub-K halves x 16 mfma_scale_f32_16x16x128_f8f6f4.
// K must be a multiple of 256 (modes 0,1,3: K=1024 -> 4 phases).
// OKIND: 1=bf16(8B, DO_EXP optional), 2=fp8(dword).
// MODE 3: QKV. by<8: Q; 8..15: K; >=16: VT. MODE 1: logits+rowsums. MODE 0: Wo.
template <int MODE, int OKIND, int DO_EXP>
__device__ __forceinline__ void gemm_core256(
    const unsigned char* __restrict__ A, int lda,
    const unsigned char* __restrict__ B, int ldb,
    void* __restrict__ Cout, void* __restrict__ Cout2, int ldc,
    int K, float alpha,
    const unsigned char* __restrict__ A1, const unsigned char* __restrict__ A2,
    float* __restrict__ sums_out, unsigned char* __restrict__ smem) {
  int bx = blockIdx.x, by = blockIdx.y;
  const unsigned char* Ab;
  const unsigned char* Bb;
  void* Cdst = Cout;
  int ldce = ldc;
  int rbase, cbase;
  int ldae = lda, ldbe = ldb;
  if constexpr (MODE == 0) {
    Ab = A + (size_t)by * 128 * lda;      // Wo rows
    Bb = B + (size_t)bx * 128 * ldb;      // y rows
    rbase = bx * 128; cbase = by * 128;
  } else if constexpr (MODE == 3) {
    if (by < 16) {
      Ab = A + (size_t)by * 128 * lda;    // Wq|Wk contiguous rows
      Bb = B + (size_t)bx * 128 * ldb;    // X rows
      if (by >= 8) Cdst = Cout2;
      rbase = bx * 128; cbase = (by & 7) * 128;
    } else {
      Ab = B + (size_t)bx * 128 * ldb;                 // X rows (qc = x)
      Bb = A1 + (size_t)(by - 16) * 128 * 1024;        // Wv rows (qr = wv)
      Cdst = (void*)const_cast<unsigned char*>(A2);    // VT [1024,12288]
      rbase = (by - 16) * 128; cbase = bx * 128;
      ldce = 3 * NSEQ;
    }
  } else {  // MODE == 1
    int s = bx >> 5, ti = bx & 31;
    int bt = ti + by - 2;                        // validity checked by caller
    Ab = A + (size_t)(s * 32 + bt) * 128 * lda;  // K rows (qc = band col)
    Bb = B + (size_t)bx * 128 * ldb;             // Q rows (qr = i)
    rbase = bx * 128; cbase = by * 128;          // ldce = 640
  }

  const int t = threadIdx.x;
  const int l = t & 63;
  const int w = t >> 6;
  const int fr = l & 15;
  const int quad = l >> 4;
  const int wm = (w >> 1) * 64;
  const int wn = (w & 1) * 64;
  const int fq4 = quad * 4;

  // staging: 8 insts per matrix per wave; inst j covers rows w*32+j*4 .. +3
  int srow[8], scg[8], sloff[8];
#pragma unroll
  for (int j = 0; j < 8; j++) {
    srow[j] = w * 32 + j * 4 + (l >> 4);
    scg[j] = ((l & 15) - srow[j]) & 15;      // global chunk for LDS slot l&15
    sloff[j] = (w * 32 + j * 4) * 256 + l * 16;
  }

  unsigned char* As = smem;
  unsigned char* Bs = smem + 32768;

  f32x4 acc[4][4];
#pragma unroll
  for (int m = 0; m < 4; m++)
#pragma unroll
    for (int n = 0; n < 4; n++) acc[m][n] = (f32x4){0.f, 0.f, 0.f, 0.f};

  const int nt = K >> 8;   // 4 phases at K=1024
  for (int tt = 0; tt < nt; tt++) {
    int kk = tt * 256;
    __syncthreads();
#pragma unroll
    for (int j = 0; j < 8; j++)
      __builtin_amdgcn_global_load_lds(
          (gvoid_t*)(Ab + (size_t)srow[j] * ldae + kk + scg[j] * 16),
          (lvoid_t*)(As + sloff[j]), 16, 0, 0);
#pragma unroll
    for (int j = 0; j < 8; j++)
      __builtin_amdgcn_global_load_lds(
          (gvoid_t*)(Bb + (size_t)srow[j] * ldbe + kk + scg[j] * 16),
          (lvoid_t*)(Bs + sloff[j]), 16, 0, 0);
    __syncthreads();
#pragma unroll
    for (int h = 0; h < 2; h++) {
      const int cb = h * 8 + quad * 2;   // global chunk base for this lane's K-block
      int8v a8[4], b8[4];
#pragma unroll
      for (int m = 0; m < 4; m++) {
        int r = wm + m * 16 + fr;
        int s0i = (cb + r) & 15, s1i = (cb + 1 + r) & 15;
        a8[m] = pack32(As + r * 256 + s0i * 16, As + r * 256 + s1i * 16);
      }
#pragma unroll
      for (int n = 0; n < 4; n++) {
        int r = wn + n * 16 + fr;
        int s0i = (cb + r) & 15, s1i = (cb + 1 + r) & 15;
        b8[n] = pack32(Bs + r * 256 + s0i * 16, Bs + r * 256 + s1i * 16);
      }
#pragma unroll
      for (int m = 0; m < 4; m++)
#pragma unroll
        for (int n = 0; n < 4; n++)
          acc[m][n] = __builtin_amdgcn_mfma_scale_f32_16x16x128_f8f6f4(
              a8[m], b8[n], acc[m][n], 0, 0, 0, 0x7F7F7F7F, 0, 0x7F7F7F7F);
    }
  }

  // direct-store epilogue; MODE 1 also accumulates the in-band row-sum of exp
  float rowsum[4] = {0.f, 0.f, 0.f, 0.f};
  const int jb = ((bx & 31) - 2) * 128;   // used only when MODE==1
#pragma unroll
  for (int m = 0; m < 4; m++) {
#pragma unroll
    for (int n = 0; n < 4; n++) {
      int oc = cbase + wm + m * 16 + fq4;
      int orow = rbase + wn + n * 16 + fr;
      float v0 = acc[m][n][0] * alpha, v1 = acc[m][n][1] * alpha;
      float v2 = acc[m][n][2] * alpha, v3 = acc[m][n][3] * alpha;
      if constexpr (OKIND == 1) {
        if constexpr (DO_EXP) {
          v0 = __expf(v0); v1 = __expf(v1); v2 = __expf(v2); v3 = __expf(v3);
          if constexpr (MODE == 1) {
            int d0 = (orow & 4095) - (jb + oc);   // i - j for element 0
            rowsum[n] += ((unsigned)(d0 + 249) < 499u ? v0 : 0.f)
                       + ((unsigned)(d0 + 248) < 499u ? v1 : 0.f)
                       + ((unsigned)(d0 + 247) < 499u ? v2 : 0.f)
                       + ((unsigned)(d0 + 246) < 499u ? v3 : 0.f);
          }
        }
        ushort4 o; o.x = f2b(v0); o.y = f2b(v1); o.z = f2b(v2); o.w = f2b(v3);
        *(uint2*)((unsigned short*)Cdst + (size_t)orow * ldce + oc) = *(uint2*)&o;
      } else {
        *(unsigned int*)((unsigned char*)Cdst + (size_t)orow * ldce + oc) =
            f2e4x4(v0, v1, v2, v3);
      }
    }
  }
  if constexpr (MODE == 1 && DO_EXP) {
    // lanes {fr, fr+16, fr+32, fr+48} hold the same rows; reduce across quads
#pragma unroll
    for (int n = 0; n < 4; n++) {
      float sv = rowsum[n];
      sv += __shfl_xor(sv, 16);
      sv += __shfl_xor(sv, 32);
      if (quad == 0) {
        int orow = rbase + wn + n * 16 + fr;
        atomicAdd(sums_out + orow, sv);
      }
    }
  }
}

// -------- fp8 GEMM core, BK=128 counted-vmcnt dbuf (r7, for banded K) --------
// Used only by k_av (MODE 2): K window not a multiple of 256.
__device__ __forceinline__ void gemm_core_av(
    const unsigned char* __restrict__ A, int lda,
    const unsigned char* __restrict__ B,
    void* __restrict__ Cout, int ldc, float alpha,
    const unsigned char* __restrict__ A1, const unsigned char* __restrict__ A2,
    unsigned char* __restrict__ smem) {
  int bx = blockIdx.x, by = blockIdx.y;
  int s = bx >> 5, ti = bx & 31;
  const unsigned char* Ab = A + (size_t)by * 128 * lda + s * NSEQ;
  const unsigned char* Bbase = (s == 0) ? B : ((s == 1) ? A1 : A2);
  const unsigned char* Bb = Bbase + (size_t)ti * 128 * 640;
  const int ldbe = 640;
  int lo = ti - 2; if (lo < 0) lo = 0;
  int hi = ti + 3; if (hi > 32) hi = 32;
  int k0 = lo * 128, k1 = hi * 128;
  int b_koff = (ti - 2) * 128;
  int rbase = bx * 128, cbase = by * 128;

  const int t = threadIdx.x;
  const int l = t & 63;
  const int w = t >> 6;
  const int fr = l & 15;
  const int quad = l >> 4;
  const int wm = (w >> 1) * 64;
  const int wn = (w & 1) * 64;
  const int fq4 = quad * 4;

  int srow[4], scg[4], sloff[4];
#pragma unroll
  for (int j = 0; j < 4; j++) {
    srow[j] = w * 32 + j * 8 + (l >> 3);
    scg[j] = ((l & 7) - srow[j]) & 7;
    sloff[j] = (w * 32 + j * 8) * 128 + l * 16;
  }

  f32x4 acc[4][4];
#pragma unroll
  for (int m = 0; m < 4; m++)
#pragma unroll
    for (int n = 0; n < 4; n++) acc[m][n] = (f32x4){0.f, 0.f, 0.f, 0.f};

  const int c0 = quad * 2;
  const int nt = (k1 - k0) >> 7;

  {
    int kk = k0, kb = kk - b_koff;
#pragma unroll
    for (int j = 0; j < 4; j++)
      __builtin_amdgcn_global_load_lds(
          (gvoid_t*)(Ab + (size_t)srow[j] * lda + kk + scg[j] * 16),
          (lvoid_t*)(smem + sloff[j]), 16, 0, 0);
#pragma unroll
    for (int j = 0; j < 4; j++)
      __builtin_amdgcn_global_load_lds(
          (gvoid_t*)(Bb + (size_t)srow[j] * ldbe + kb + scg[j] * 16),
          (lvoid_t*)(smem + 16384 + sloff[j]), 16, 0, 0);
  }

  for (int tt = 0; tt < nt; tt++) {
    if (tt + 1 < nt) {
      int kk = k0 + (tt + 1) * 128, kb = kk - b_koff;
      unsigned char* Asn = smem + ((tt + 1) & 1) * 32768;
#pragma unroll
      for (int j = 0; j < 4; j++)
        __builtin_amdgcn_global_load_lds(
            (gvoid_t*)(Ab + (size_t)srow[j] * lda + kk + scg[j] * 16),
            (lvoid_t*)(Asn + sloff[j]), 16, 0, 0);
#pragma unroll
      for (int j = 0; j < 4; j++)
        __builtin_amdgcn_global_load_lds(
            (gvoid_t*)(Bb + (size_t)srow[j] * ldbe + kb + scg[j] * 16),
            (lvoid_t*)(Asn + 16384 + sloff[j]), 16, 0, 0);
      __builtin_amdgcn_sched_barrier(0);
      asm volatile("s_waitcnt vmcnt(8)" ::: "memory");
    } else {
      asm volatile("s_waitcnt vmcnt(0)" ::: "memory");
    }
    asm volatile("s_barrier" ::: "memory");

    const unsigned char* Asc = smem + (tt & 1) * 32768;
    const unsigned char* Bsc = Asc + 16384;
    int8v a8[4], b8[4];
#pragma unroll
    for (int m = 0; m < 4; m++) {
      int r = wm + m * 16 + fr;
      int s0i = (c0 + r) & 7, s1i = (s0i + 1) & 7;
      a8[m] = pack32(Asc + r * 128 + s0i * 16, Asc + r * 128 + s1i * 16);
    }
#pragma unroll
    for (int n = 0; n < 4; n++) {
      int r = wn + n * 16 + fr;
      int s0i = (c0 + r) & 7, s1i = (s0i + 1) & 7;
      b8[n] = pack32(Bsc + r * 128 + s0i * 16, Bsc + r * 128 + s1i * 16);
    }
#pragma unroll
    for (int m = 0; m < 4; m++)
#pragma unroll
      for (int n = 0; n < 4; n++)
        acc[m][n] = __builtin_amdgcn_mfma_scale_f32_16x16x128_f8f6f4(
            a8[m], b8[n], acc[m][n], 0, 0, 0, 0x7F7F7F7F, 0, 0x7F7F7F7F);
    asm volatile("s_barrier" ::: "memory");
  }

#pragma unroll
  for (int m = 0; m < 4; m++) {
#pragma unroll
    for (int n = 0; n < 4; n++) {
      int oc = cbase + wm + m * 16 + fq4;
      int orow = rbase + wn + n * 16 + fr;
      float v0 = acc[m][n][0] * alpha, v1 = acc[m][n][1] * alpha;
      float v2 = acc[m][n][2] * alpha, v3 = acc[m][n][3] * alpha;
      *(unsigned int*)((unsigned char*)Cout + (size_t)orow * ldc + oc) =
          f2e4x4(v0, v1, v2, v3);
    }
  }
}

// QKV fp8 (BK=256)
__global__ __launch_bounds__(256) void k_qkv(
    const unsigned char* __restrict__ A, const unsigned char* __restrict__ B,
    void* __restrict__ Cout, void* __restrict__ Cout2, float alpha,
    const unsigned char* __restrict__ A1, const unsigned char* __restrict__ A2) {
  __shared__ unsigned char smem[2 * 128 * 256];  // 64 KB: A 32K | B 32K
  gemm_core256<3, 2, 0>(A, 1024, B, 1024, Cout, Cout2, 1024, 1024, alpha,
                        A1, A2, nullptr, smem);
}

// logits -> Eband (exp) + fused band row-sums (BK=256)
__global__ __launch_bounds__(256) void k_logits(
    const unsigned char* __restrict__ A, const unsigned char* __restrict__ B,
    void* __restrict__ Cout, float alpha, float* __restrict__ sums) {
  int ti = blockIdx.x & 31;
  int bt = ti + (int)blockIdx.y - 2;
  if (bt < 0 || bt >= 32) return;   // whole-block, before any barrier
  __shared__ unsigned char smem[2 * 128 * 256];
  gemm_core256<1, 1, 1>(A, 1024, B, 1024, Cout, nullptr, 640, 1024, alpha,
                        nullptr, nullptr, sums, smem);
}

// y = attT @ V (banded K window; r7 core)
__global__ __launch_bounds__(256) void k_av(
    const unsigned char* __restrict__ A, const unsigned char* __restrict__ B,
    void* __restrict__ Cout, float alpha,
    const unsigned char* __restrict__ A1, const unsigned char* __restrict__ A2) {
  __shared__ unsigned char smem[4 * 128 * 128];
  gemm_core_av(A, 3 * NSEQ, B, Cout, 1024, alpha, A1, A2, smem);
}

// yo = y @ Wo^T (bf16 out, no exp; BK=256)
__global__ __launch_bounds__(256) void k_wo(
    const unsigned char* __restrict__ A, const unsigned char* __restrict__ B,
    void* __restrict__ Cout, float alpha) {
  __shared__ unsigned char smem[2 * 128 * 256];
  gemm_core256<0, 1, 0>(A, 1024, B, 1024, Cout, nullptr, 1024, 1024, alpha,
                        nullptr, nullptr, nullptr, smem);
}

// -------- small bf16 GEMM: 64x64 tile, BK=64, 2-phase dbuf --------
// A = weight (qc dim), B = activation (qr dim).
__global__ __launch_bounds__(256) void k_gemm64(
    const unsigned short* __restrict__ A, int lda,
    const unsigned short* __restrict__ B, int ldb,
    void* __restrict__ Cout, int ldc, int K,
    const float* __restrict__ bias, int relu, int out_bf16) {
  __shared__ unsigned short smem[4 * 64 * 64];  // 32 KB: 2 bufs x (A | B)
  int bx = blockIdx.x, by = blockIdx.y;
  const unsigned short* Ab = A + (size_t)by * 64 * lda;   // weight rows
  const unsigned short* Bb = B + (size_t)bx * 64 * ldb;   // activation rows
  int rbase = bx * 64, cbase = by * 64;

  const int t = threadIdx.x;
  const int l = t & 63;
  const int w = t >> 6;
  const int fr = l & 15;
  const int quad = l >> 4;
  const int wm = (w & 1) * 32;
  const int wn = (w >> 1) * 32;
  const int fq4 = quad * 4;

  int srow[2], scg[2], sloff[2];
#pragma unroll
  for (int j = 0; j < 2; j++) {
    srow[j] = w * 16 + j * 8 + (l >> 3);
    scg[j] = ((l & 7) - srow[j]) & 7;
    sloff[j] = (w * 16 + j * 8) * 64 + l * 8;
  }

  f32x4 acc[2][2];
#pragma unroll
  for (int m = 0; m < 2; m++)
#pragma unroll
    for (int n = 0; n < 2; n++) acc[m][n] = (f32x4){0.f, 0.f, 0.f, 0.f};

  const int nt = K >> 6;

  // prologue: stage tile 0 -> buf 0
#pragma unroll
  for (int j = 0; j < 2; j++)
    __builtin_amdgcn_global_load_lds(
        (gvoid_t*)(Ab + (size_t)srow[j] * lda + scg[j] * 8),
        (lvoid_t*)(smem + sloff[j]), 16, 0, 0);
#pragma unroll
  for (int j = 0; j < 2; j++)
    __builtin_amdgcn_global_load_lds(
        (gvoid_t*)(Bb + (size_t)srow[j] * ldb + scg[j] * 8),
        (lvoid_t*)(smem + 4096 + sloff[j]), 16, 0, 0);

  for (int tt = 0; tt < nt; tt++) {
    __syncthreads();   // buf[tt&1] ready; all waves done reading buf[(tt+1)&1]
    if (tt + 1 < nt) {
      int kk = (tt + 1) * 64;
      unsigned short* Asn = smem + ((tt + 1) & 1) * 8192;
#pragma unroll
      for (int j = 0; j < 2; j++)
        __builtin_amdgcn_global_load_lds(
            (gvoid_t*)(Ab + (size_t)srow[j] * lda + kk + scg[j] * 8),
            (lvoid_t*)(Asn + sloff[j]), 16, 0, 0);
#pragma unroll
      for (int j = 0; j < 2; j++)
        __builtin_amdgcn_global_load_lds(
            (gvoid_t*)(Bb + (size_t)srow[j] * ldb + kk + scg[j] * 8),
            (lvoid_t*)(Asn + 4096 + sloff[j]), 16, 0, 0);
    }
    const unsigned short* Asc = smem + (tt & 1) * 8192;
    const unsigned short* Bsc = Asc + 4096;
#pragma unroll
    for (int s = 0; s < 2; s++) {
      short8 af[2], bf[2];
#pragma unroll
      for (int m = 0; m < 2; m++) {
        int r = wm + m * 16 + fr;
        int slot = (s * 4 + quad + r) & 7;
        af[m] = *(const short8*)(Asc + r * 64 + slot * 8);
      }
#pragma unroll
      for (int n = 0; n < 2; n++) {
        int r = wn + n * 16 + fr;
        int slot = (s * 4 + quad + r) & 7;
        bf[n] = *(const short8*)(Bsc + r * 64 + slot * 8);
      }
#pragma unroll
      for (int m = 0; m < 2; m++)
#pragma unroll
        for (int n = 0; n < 2; n++)
          acc[m][n] = __builtin_amdgcn_mfma_f32_16x16x32_bf16(af[m], bf[n], acc[m][n], 0, 0, 0);
    }
  }

#pragma unroll
  for (int m = 0; m < 2; m++) {
#pragma unroll
    for (int n = 0; n < 2; n++) {
      int oc = cbase + wm + m * 16 + fq4;
      int orow = rbase + wn + n * 16 + fr;
      float4 bv = bias ? *(const float4*)(bias + oc) : make_float4(0.f, 0.f, 0.f, 0.f);
      float v0 = acc[m][n][0] + bv.x, v1 = acc[m][n][1] + bv.y;
      float v2 = acc[m][n][2] + bv.z, v3 = acc[m][n][3] + bv.w;
      if (relu) {
        v0 = fmaxf(v0, 0.f); v1 = fmaxf(v1, 0.f);
        v2 = fmaxf(v2, 0.f); v3 = fmaxf(v3, 0.f);
      }
      if (out_bf16) {
        ushort4 o; o.x = f2b(v0); o.y = f2b(v1); o.z = f2b(v2); o.w = f2b(v3);
        *(uint2*)((unsigned short*)Cout + (size_t)orow * ldc + oc) = *(uint2*)&o;
      } else {
        *(float4*)((float*)Cout + (size_t)orow * ldc + oc) = make_float4(v0, v1, v2, v3);
      }
    }
  }
}

// -------- merged: build banded attT (480 blocks) + write full fp32 att (4096) ----
__global__ __launch_bounds__(256) void k_attw(const unsigned short* __restrict__ Eband,
                                              const float* __restrict__ sums,
                                              unsigned char* __restrict__ t0,
                                              unsigned char* __restrict__ t1,
                                              unsigned char* __restrict__ t2,
                                              float* __restrict__ att) {
  __shared__ unsigned char T[128][132];  // used by build path only
  int bid = blockIdx.x;
  if (bid < 480) {
    int tjoff = bid % 5;                 // was blockIdx.x of k_build_attT
    int byy = bid / 5;                   // was blockIdx.y
    int s = byy >> 5, ti = byy & 31;     // i tile (attT rows), local
    int tj = ti + tjoff - 2;             // j tile
    if (tj < 0 || tj >= 32) return;
    unsigned char* dst = (s == 0) ? t0 : ((s == 1) ? t1 : t2);
    int t = threadIdx.x;
    int c0 = (ti - tj + 2) * 128;  // Eband col base for rows j reading i-tile ti
    int colg = (t & 31) * 4;       // i_loc
    for (int jj = t >> 5; jj < 128; jj += 8) {
      int jg = s * NSEQ + tj * 128 + jj;
      float inv = 16.f / sums[jg];
      ushort4 v = *(const ushort4*)&Eband[(size_t)jg * 640 + c0 + colg];
      float vv[4] = {b2f(v.x), b2f(v.y), b2f(v.z), b2f(v.w)};
#pragma unroll
      for (int q = 0; q < 4; q++) {
        int i = ti * 128 + colg + q;
        int d = i - (tj * 128 + jj);
        float a = (d < 250 && d > -250) ? vv[q] * inv : 0.f;
        T[colg + q][jj] = f2e4(a);
      }
    }
    __syncthreads();
    int jb0 = (tj - ti + 2) * 128;  // banded col base in attT rows of tile ti
    for (int ii = t >> 5; ii < 128; ii += 8) {
      size_t o = (size_t)(ti * 128 + ii) * 640 + jb0 + colg;
      *(unsigned int*)(dst + o) = *(const unsigned int*)&T[ii][colg];
    }
  } else {
    int i = bid - 480;                   // row 0..4095
    int ti = i >> 7, cbase = (ti - 2) * 128;
    int jlo = i - 249; if (jlo < 0) jlo = 0;
    int jhi = i + 249; if (jhi > NSEQ - 1) jhi = NSEQ - 1;
    float inv = 1.f / sums[i];
    const unsigned short* L = Eband + (size_t)i * 640;
    float* arow = att + (size_t)i * NSEQ;
    for (int j0 = threadIdx.x * 4; j0 < NSEQ; j0 += 1024) {
      float ov[4];
#pragma unroll
      for (int q = 0; q < 4; q++) {
        int j = j0 + q;
        ov[q] = (j >= jlo && j <= jhi) ? b2f(L[j - cbase]) * inv : 0.f;
      }
      *(float4*)(arow + j0) = make_float4(ov[0], ov[1], ov[2], ov[3]);
    }
  }
}

// -------- residual + LayerNorm (ddof=1, eps on std) for 3 streams, sum -> bf16 --------
__global__ __launch_bounds__(256) void k_ln3(const unsigned short* __restrict__ yo,
                                             const float* __restrict__ x1,
                                             const float* __restrict__ x2,
                                             const float* __restrict__ x3,
                                             const float* __restrict__ g,
                                             const float* __restrict__ b,
                                             unsigned short* __restrict__ ysum_b) {
  int i = blockIdx.x, t = threadIdx.x;
  int w = t >> 6, lane = t & 63;
  __shared__ float red[8];
  const float* xs[3] = {x1, x2, x3};
  float4 gg = *(const float4*)(g + t * 4);
  float4 bb = *(const float4*)(b + t * 4);
  float acc[4] = {0.f, 0.f, 0.f, 0.f};
  for (int s = 0; s < 3; s++) {
    ushort4 yv = *(const ushort4*)(yo + ((size_t)(s * NSEQ + i)) * MDIM + t * 4);
    float4 xx = *(const float4*)(xs[s] + (size_t)i * MDIM + t * 4);
    float v[4] = {b2f(yv.x) + xx.x, b2f(yv.y) + xx.y, b2f(yv.z) + xx.z, b2f(yv.w) + xx.w};
    float s1 = v[0] + v[1] + v[2] + v[3];
    float s2 = v[0]*v[0] + v[1]*v[1] + v[2]*v[2] + v[3]*v[3];
    for (int off = 32; off; off >>= 1) { s1 += __shfl_xor(s1, off); s2 += __shfl_xor(s2, off); }
    __syncthreads();
    if (lane == 0) { red[w] = s1; red[4 + w] = s2; }
    __syncthreads();
    float S1 = red[0] + red[1] + red[2] + red[3];
    float S2 = red[4] + red[5] + red[6] + red[7];
    float mean = S1 * (1.f / 1024.f);
    float var = (S2 - S1 * mean) * (1.f / 1023.f);
    float rstd = 1.f / (sqrtf(var) + 1e-6f);
    acc[0] += gg.x * (v[0] - mean) * rstd + bb.x;
    acc[1] += gg.y * (v[1] - mean) * rstd + bb.y;
    acc[2] += gg.z * (v[2] - mean) * rstd + bb.z;
    acc[3] += gg.w * (v[3] - mean) * rstd + bb.w;
  }
  ushort4 o;
  o.x = f2b(acc[0]); o.y = f2b(acc[1]); o.z = f2b(acc[2]); o.w = f2b(acc[3]);
  *(ushort4*)(ysum_b + (size_t)i * MDIM + t * 4) = o;
}

// -------- final: LN(128, gkc/bkc) -> dot(kd_w) + kd_b -> sigmoid --------
__global__ __launch_bounds__(128) void k_final(const float* __restrict__ h3,
                                               const float* __restrict__ g,
                                               const float* __restrict__ b,
                                               const float* __restrict__ kdw,
                                               const float* __restrict__ kdb,
                                               float* __restrict__ yout) {
  int i = blockIdx.x, t = threadIdx.x;
  float v = h3[(size_t)i * 128 + t];
  float s1 = v, s2 = v * v;
  for (int off = 32; off; off >>= 1) { s1 += __shfl_xor(s1, off); s2 += __shfl_xor(s2, off); }
  __shared__ float red[4];
  int w = t >> 6, lane = t & 63;
  if (lane == 0) { red[w] = s1; red[2 + w] = s2; }
  __syncthreads();
  float S1 = red[0] + red[1], S2 = red[2] + red[3];
  float mean = S1 * (1.f / 128.f);
  float var = (S2 - S1 * mean) * (1.f / 127.f);
  float rstd = 1.f / (sqrtf(var) + 1e-6f);
  float ln = g[t] * (v - mean) * rstd + b[t];
  float p = ln * kdw[t];
  for (int off = 32; off; off >>= 1) p += __shfl_xor(p, off);
  __syncthreads();
  if (lane == 0) red[w] = p;
  __syncthreads();
  if (t == 0) {
    float z = red[0] + red[1] + kdb[0];
    yout[i] = 1.f / (1.f + __expf(-z));
  }
}

extern "C" void kernel_launch(void* const* d_in, const int* in_sizes, int n_in,
                              void* d_out, int out_size, void* d_ws, size_t ws_size,
                              hipStream_t stream) {
  const float* x1 = (const float*)d_in[0];
  const float* x2 = (const float*)d_in[1];
  const float* x3 = (const float*)d_in[2];
  const float* Wq = (const float*)d_in[3];
  const float* Wk = (const float*)d_in[4];
  const float* Wv = (const float*)d_in[5];
  const float* Wo = (const float*)d_in[6];
  const float* ka_w = (const float*)d_in[7];
  const float* ka_b = (const float*)d_in[8];
  const float* kb_w = (const float*)d_in[9];
  const float* kb_b = (const float*)d_in[10];
  const float* kc_w = (const float*)d_in[11];
  const float* kc_b = (const float*)d_in[12];
  const float* kd_w = (const float*)d_in[13];
  const float* kd_b = (const float*)d_in[14];
  const float* g13 = (const float*)d_in[15];
  const float* b13 = (const float*)d_in[16];
  const float* gkc = (const float*)d_in[17];
  const float* bkc = (const float*)d_in[18];

  float* y_out = (float*)d_out;
  float* att_out = y_out + NSEQ;  // [4096,4096] fp32

  char* ws = (char*)d_ws;
  size_t off = 0;
  auto alloc = [&](size_t bytes) -> void* {
    void* p = ws + off;
    off += (bytes + 255) & ~(size_t)255;
    return p;
  };
  const size_t NM = (size_t)3 * NSEQ * MDIM;  // 12.6M elems
  // fp8 attention weights, contiguous: Wq|Wk|Wv|Wo (x64 scaled)
  unsigned char* Wf = (unsigned char*)alloc(4 * 1048576);
  // bf16 MLP weights, contiguous: ka|kb|kc
  unsigned short* Wmlp = (unsigned short*)alloc((1048576 + 524288 + 65536) * 2);
  unsigned char* Xf = (unsigned char*)alloc(NM);      // later: yb fp8, then h1b bf16
  unsigned char* Qf = (unsigned char*)alloc(NM);      // yo bf16 spans Qf+Kf; later h2b
  unsigned char* Kf = (unsigned char*)alloc(NM);
  unsigned char* VTf = (unsigned char*)alloc(NM);     // later: ysum_b bf16 (8MB)
  unsigned short* Eband = (unsigned short*)alloc((size_t)3 * NSEQ * 640 * 2);
  float* sums = (float*)alloc((size_t)3 * NSEQ * 4);
  unsigned char* aT0 = (unsigned char*)alloc((size_t)NSEQ * 640);  // later: h3 f32
  unsigned char* aT1 = (unsigned char*)alloc((size_t)NSEQ * 640);
  unsigned char* aT2 = (unsigned char*)alloc((size_t)NSEQ * 640);
  // weight sub-pointers
  unsigned char* Wv_f = Wf + 2097152;
  unsigned char* Wo_f = Wf + 3145728;
  unsigned short* ka_b16 = Wmlp;
  unsigned short* kb_b16 = Wmlp + 1048576;
  unsigned short* kc_b16 = Wmlp + 1572864;
  // aliases (lifetimes disjoint)
  unsigned char* yb = Xf;                       // fp8 [12288,1024] = 8*y
  unsigned short* yo = (unsigned short*)Qf;     // bf16 [12288,1024] spans Qf..Kf
  unsigned short* ysum_b = (unsigned short*)VTf;// bf16 [4096,1024]
  unsigned short* h1b = (unsigned short*)Xf;    // bf16 [4096,1024]
  unsigned short* h2b = (unsigned short*)Qf;    // bf16 [4096,512]
  float* h3 = (float*)aT0;                      // f32 [4096,128]

  // all conversions + sums zero-init in one dispatch
  k_cvt_all<<<17996, 256, 0, stream>>>(Wq, Wk, Wv, Wo, ka_w, kb_w, kc_w,
                                       x1, x2, x3, Wf, Wmlp, Xf, sums);

  // merged Q+K+VT fp8: Q/K: A=Wq|Wk, B=X; VT: A=X, B=Wv
  k_qkv<<<dim3(96, 24), 256, 0, stream>>>(Wf, Xf, Qf, Kf, 1.f / 64.f, Wv_f, VTf);
  // banded logits -> E = exp(0.06 * Q.K) bf16 [12288,640] + fused band row-sums
  k_logits<<<dim3(96, 5), 256, 0, stream>>>(Kf, Qf, Eband, 0.06f, sums);
  // merged: banded attT build + full fp32 att write
  k_attw<<<4576, 256, 0, stream>>>(Eband, sums, aT0, aT1, aT2, att_out);
  // yb = 8*y: A=VT (v minor), B=attT banded; (16att)@V * 0.5, fp8 out
  k_av<<<dim3(96, 8), 256, 0, stream>>>(VTf, aT0, yb, 0.5f, aT1, aT2);
  // yo = y @ Wo^T (bf16 out): A=Wo, B=y; (8y)@(64Wo) * 1/512
  k_wo<<<dim3(96, 8), 256, 0, stream>>>(Wo_f, yb, yo, 1.f / 512.f);
  // residual + LN + 3-stream sum -> bf16
  k_ln3<<<4096, 256, 0, stream>>>(yo, x1, x2, x3, g13, b13, ysum_b);

  // MLP head (bf16, 64x64 tiles dbuf, A=weight)
  k_gemm64<<<dim3(64, 16), 256, 0, stream>>>(ka_b16, 1024, ysum_b, 1024, h1b, 1024,
                                             1024, ka_b, 0, 1);
  k_gemm64<<<dim3(64, 8), 256, 0, stream>>>(kb_b16, 1024, h1b, 1024, h2b, 512,
                                            1024, kb_b, 0, 1);
  k_gemm64<<<dim3(64, 2), 256, 0, stream>>>(kc_b16, 512, h2b, 512, h3, 128,
                                            512, kc_b, 1, 0);
  k_final<<<4096, 128, 0, stream>>>(h3, gkc, bkc, kd_w, kd_b, y_out);
}

// Round 13
// 314.960 us; speedup vs baseline: 1.2514x; 1.0252x over previous
//
#include <hip/hip_runtime.h>
#include <hip/hip_bf16.h>
#include <cstdint>
#include <cstddef>

// Problem constants
#define NSEQ 4096
#define MDIM 1024
// band: |i-j| < 250 -> row-tile ti needs col-tiles [ti-2, ti+2]
// banded layout (Eband bf16 = exp(logits), attT fp8 x16): row i, col c = j - 128*((i>>7)-2), width 640
// fp8 scaling: attn weights x64, attT x16, y stored x8; MLP kept bf16 for accuracy.
// GEMM operand rule: A = matrix indexing the OUTPUT'S MINOR DIM.
// MFMA: MX-scaled mfma_f32_16x16x128_f8f6f4, unit scales (0x7F=2^0), 2x fp8 rate.
// r12 analysis: BK=256 gave only -1.7us -> per-phase wait scales with BYTES, and
//   FETCH_SIZE ~= input size -> reads are cache-served; but Xf (12MB) >> 4MB
//   per-XCD L2 and round-robin block->XCD spreads every bx over all XCDs -> L2
//   thrash, loads served by slower LLC. r13: T1 XCD swizzle: flatten grid to 1D,
//   XCD k (bid&7) owns bx window [12k,12k+12) across all by -> per-XCD B-operand
//   footprint 1.5MB (fits L2). Bijective (all grids % 8 == 0). Bit-identical.
// r11/r12: BK=256 single-buffer 2-barrier core for K=1024 GEMMs; k_av keeps r7
//   counted-vmcnt BK=128 core (banded K-window).
// r8/r9 lesson: per-lane A-from-global stalls (compiler-tracked waits). REVERTED.
// r4 lesson: 128^2 MLP tile -> grid collapse. MLP = dbuf 64^2 k_gemm64.

typedef __attribute__((ext_vector_type(8))) short short8;
typedef __attribute__((ext_vector_type(4))) float f32x4;
typedef __attribute__((ext_vector_type(2))) long long2v;
typedef __attribute__((ext_vector_type(8))) int int8v;
typedef __attribute__((ext_vector_type(4))) int int4v;

typedef const __attribute__((address_space(1))) void gvoid_t;
typedef __attribute__((address_space(3))) void lvoid_t;

__device__ __forceinline__ unsigned short f2b(float x) {
  union { float f; unsigned int u; } a; a.f = x;
  unsigned int r = (a.u + 0x7fffu + ((a.u >> 16) & 1u)) >> 16;
  return (unsigned short)r;
}
__device__ __forceinline__ float b2f(unsigned short u) {
  union { float f; unsigned int u32; } a; a.u32 = ((unsigned int)u) << 16;
  return a.f;
}
__device__ __forceinline__ unsigned char f2e4(float x) {
  return (unsigned char)(__builtin_amdgcn_cvt_pk_fp8_f32(x, x, 0, false) & 0xff);
}
__device__ __forceinline__ unsigned int f2e4x4(float a, float b, float c, float d) {
  unsigned int lo = __builtin_amdgcn_cvt_pk_fp8_f32(a, b, 0, false);
  return (unsigned int)__builtin_amdgcn_cvt_pk_fp8_f32(c, d, lo, true);
}

__device__ __forceinline__ int8v pack32(const unsigned char* p0,
                                        const unsigned char* p1) {
  int4v lo = *(const int4v*)p0;
  int4v hi = *(const int4v*)p1;
  int8v r;
  r[0] = lo[0]; r[1] = lo[1]; r[2] = lo[2]; r[3] = lo[3];
  r[4] = hi[0]; r[5] = hi[1]; r[6] = hi[2]; r[7] = hi[3];
  return r;
}

// XCD-chunked decode: XCD k = bid&7 owns bx window [12k, 12k+12) for all by.
// Requires gridDim.x % 8 == 0 and 96 bx per by. Bijective.
__device__ __forceinline__ void xcd_decode(int bid, int& bx, int& by) {
  int slot = bid >> 3;
  bx = (bid & 7) * 12 + slot % 12;
  by = slot / 12;
}

// -------- merged cvt: Wq..Wo (x64)->fp8, ka/kb/kc->bf16, x1..x3->fp8, zero sums ----
__global__ __launch_bounds__(256) void k_cvt_all(
    const float* __restrict__ s0, const float* __restrict__ s1,
    const float* __restrict__ s2, const float* __restrict__ s3,
    const float* __restrict__ s4, const float* __restrict__ s5,
    const float* __restrict__ s6,
    const float* __restrict__ xa, const float* __restrict__ xb,
    const float* __restrict__ xc,
    unsigned char* __restrict__ Wf8, unsigned short* __restrict__ Wmlp,
    unsigned char* __restrict__ Xdst, float* __restrict__ sums) {
  int idx = blockIdx.x * 256 + threadIdx.x;  // chunk of 4 floats
  if (idx < 1048576) {  // Wq,Wk,Wv,Wo fp8 x64
    int seg = idx >> 18, local = idx & 262143;
    const float* src = (seg == 0) ? s0 : (seg == 1) ? s1 : (seg == 2) ? s2 : s3;
    float4 v = *(const float4*)(src + (size_t)local * 4);
    *(unsigned int*)(Wf8 + (size_t)idx * 4) =
        f2e4x4(v.x * 64.f, v.y * 64.f, v.z * 64.f, v.w * 64.f);
  } else if (idx < 1458176) {  // ka,kb,kc bf16
    int i2 = idx - 1048576;
    const float* src; int local;
    if (i2 < 262144) { src = s4; local = i2; }
    else if (i2 < 393216) { src = s5; local = i2 - 262144; }
    else { src = s6; local = i2 - 393216; }
    float4 v = *(const float4*)(src + (size_t)local * 4);
    ushort4 o; o.x = f2b(v.x); o.y = f2b(v.y); o.z = f2b(v.z); o.w = f2b(v.w);
    *(ushort4*)(Wmlp + (size_t)i2 * 4) = o;
  } else if (idx < 4603904) {  // x1..x3 fp8
    int i2 = idx - 1458176;   // 0 .. 3*2^20-1
    int seg = i2 >> 20, local = i2 & 1048575;
    const float* src = (seg == 0) ? xa : (seg == 1) ? xb : xc;
    float4 v = *(const float4*)(src + (size_t)local * 4);
    *(unsigned int*)(Xdst + (size_t)i2 * 4) = f2e4x4(v.x, v.y, v.z, v.w);
  } else {  // zero softmax denominators (12288 floats)
    int i3 = idx - 4603904;   // 0..3071
    *(float4*)(sums + (size_t)i3 * 4) = make_float4(0.f, 0.f, 0.f, 0.f);
  }
}

// -------- fp8 GEMM core, BK=256, single-buffer 2-barrier --------
// A tile 128x256 (32KB) + B tile 128x256 (32KB); LDS row = 256B = 16 slots of 16B;
// slot s of row r holds global chunk (s-r)&15 (rotation swizzle). Per phase:
// 16 gload_lds/wave, 2 sub-K halves x 16 mfma_scale_f32_16x16x128_f8f6f4.
// K must be a multiple of 256 (modes 0,1,3: K=1024 -> 4 phases).
// OKIND: 1=bf16(8B, DO_EXP optional), 2=fp8(dword).
// MODE 3: QKV. by<8: Q; 8..15: K; >=16: VT. MODE 1: logits+rowsums. MODE 0: Wo.
template <int MODE, int OKIND, int DO_EXP>
__device__ __forceinline__ void gemm_core256(
    int bx, int by,
    const unsigned char* __restrict__ A, int lda,
    const unsigned char* __restrict__ B, int ldb,
    void* __restrict__ Cout, void* __restrict__ Cout2, int ldc,
    int K, float alpha,
    const unsigned char* __restrict__ A1, const unsigned char* __restrict__ A2,
    float* __restrict__ sums_out, unsigned char* __restrict__ smem) {
  const unsigned char* Ab;
  const unsigned char* Bb;
  void* Cdst = Cout;
  int ldce = ldc;
  int rbase, cbase;
  int ldae = lda, ldbe = ldb;
  if constexpr (MODE == 0) {
    Ab = A + (size_t)by * 128 * lda;      // Wo rows
    Bb = B + (size_t)bx * 128 * ldb;      // y rows
    rbase = bx * 128; cbase = by * 128;
  } else if constexpr (MODE == 3) {
    if (by < 16) {
      Ab = A + (size_t)by * 128 * lda;    // Wq|Wk contiguous rows
      Bb = B + (size_t)bx * 128 * ldb;    // X rows
      if (by >= 8) Cdst = Cout2;
      rbase = bx * 128; cbase = (by & 7) * 128;
    } else {
      Ab = B + (size_t)bx * 128 * ldb;                 // X rows (qc = x)
      Bb = A1 + (size_t)(by - 16) * 128 * 1024;        // Wv rows (qr = wv)
      Cdst = (void*)const_cast<unsigned char*>(A2);    // VT [1024,12288]
      rbase = (by - 16) * 128; cbase = bx * 128;
      ldce = 3 * NSEQ;
    }
  } else {  // MODE == 1
    int s = bx >> 5, ti = bx & 31;
    int bt = ti + by - 2;                        // validity checked by caller
    Ab = A + (size_t)(s * 32 + bt) * 128 * lda;  // K rows (qc = band col)
    Bb = B + (size_t)bx * 128 * ldb;             // Q rows (qr = i)
    rbase = bx * 128; cbase = by * 128;          // ldce = 640
  }

  const int t = threadIdx.x;
  const int l = t & 63;
  const int w = t >> 6;
  const int fr = l & 15;
  const int quad = l >> 4;
  const int wm = (w >> 1) * 64;
  const int wn = (w & 1) * 64;
  const int fq4 = quad * 4;

  // staging: 8 insts per matrix per wave; inst j covers rows w*32+j*4 .. +3
  int srow[8], scg[8], sloff[8];
#pragma unroll
  for (int j = 0; j < 8; j++) {
    srow[j] = w * 32 + j * 4 + (l >> 4);
    scg[j] = ((l & 15) - srow[j]) & 15;      // global chunk for LDS slot l&15
    sloff[j] = (w * 32 + j * 4) * 256 + l * 16;
  }

  unsigned char* As = smem;
  unsigned char* Bs = smem + 32768;

  f32x4 acc[4][4];
#pragma unroll
  for (int m = 0; m < 4; m++)
#pragma unroll
    for (int n = 0; n < 4; n++) acc[m][n] = (f32x4){0.f, 0.f, 0.f, 0.f};

  const int nt = K >> 8;   // 4 phases at K=1024
  for (int tt = 0; tt < nt; tt++) {
    int kk = tt * 256;
    __syncthreads();
#pragma unroll
    for (int j = 0; j < 8; j++)
      __builtin_amdgcn_global_load_lds(
          (gvoid_t*)(Ab + (size_t)srow[j] * ldae + kk + scg[j] * 16),
          (lvoid_t*)(As + sloff[j]), 16, 0, 0);
#pragma unroll
    for (int j = 0; j < 8; j++)
      __builtin_amdgcn_global_load_lds(
          (gvoid_t*)(Bb + (size_t)srow[j] * ldbe + kk + scg[j] * 16),
          (lvoid_t*)(Bs + sloff[j]), 16, 0, 0);
    __syncthreads();
#pragma unroll
    for (int h = 0; h < 2; h++) {
      const int cb = h * 8 + quad * 2;   // global chunk base for this lane's K-block
      int8v a8[4], b8[4];
#pragma unroll
      for (int m = 0; m < 4; m++) {
        int r = wm + m * 16 + fr;
        int s0i = (cb + r) & 15, s1i = (cb + 1 + r) & 15;
        a8[m] = pack32(As + r * 256 + s0i * 16, As + r * 256 + s1i * 16);
      }
#pragma unroll
      for (int n = 0; n < 4; n++) {
        int r = wn + n * 16 + fr;
        int s0i = (cb + r) & 15, s1i = (cb + 1 + r) & 15;
        b8[n] = pack32(Bs + r * 256 + s0i * 16, Bs + r * 256 + s1i * 16);
      }
#pragma unroll
      for (int m = 0; m < 4; m++)
#pragma unroll
        for (int n = 0; n < 4; n++)
          acc[m][n] = __builtin_amdgcn_mfma_scale_f32_16x16x128_f8f6f4(
              a8[m], b8[n], acc[m][n], 0, 0, 0, 0x7F7F7F7F, 0, 0x7F7F7F7F);
    }
  }

  // direct-store epilogue; MODE 1 also accumulates the in-band row-sum of exp
  float rowsum[4] = {0.f, 0.f, 0.f, 0.f};
  const int jb = ((bx & 31) - 2) * 128;   // used only when MODE==1
#pragma unroll
  for (int m = 0; m < 4; m++) {
#pragma unroll
    for (int n = 0; n < 4; n++) {
      int oc = cbase + wm + m * 16 + fq4;
      int orow = rbase + wn + n * 16 + fr;
      float v0 = acc[m][n][0] * alpha, v1 = acc[m][n][1] * alpha;
      float v2 = acc[m][n][2] * alpha, v3 = acc[m][n][3] * alpha;
      if constexpr (OKIND == 1) {
        if constexpr (DO_EXP) {
          v0 = __expf(v0); v1 = __expf(v1); v2 = __expf(v2); v3 = __expf(v3);
          if constexpr (MODE == 1) {
            int d0 = (orow & 4095) - (jb + oc);   // i - j for element 0
            rowsum[n] += ((unsigned)(d0 + 249) < 499u ? v0 : 0.f)
                       + ((unsigned)(d0 + 248) < 499u ? v1 : 0.f)
                       + ((unsigned)(d0 + 247) < 499u ? v2 : 0.f)
                       + ((unsigned)(d0 + 246) < 499u ? v3 : 0.f);
          }
        }
        ushort4 o; o.x = f2b(v0); o.y = f2b(v1); o.z = f2b(v2); o.w = f2b(v3);
        *(uint2*)((unsigned short*)Cdst + (size_t)orow * ldce + oc) = *(uint2*)&o;
      } else {
        *(unsigned int*)((unsigned char*)Cdst + (size_t)orow * ldce + oc) =
            f2e4x4(v0, v1, v2, v3);
      }
    }
  }
  if constexpr (MODE == 1 && DO_EXP) {
    // lanes {fr, fr+16, fr+32, fr+48} hold the same rows; reduce across quads
#pragma unroll
    for (int n = 0; n < 4; n++) {
      float sv = rowsum[n];
      sv += __shfl_xor(sv, 16);
      sv += __shfl_xor(sv, 32);
      if (quad == 0) {
        int orow = rbase + wn + n * 16 + fr;
        atomicAdd(sums_out + orow, sv);
      }
    }
  }
}

// -------- fp8 GEMM core, BK=128 counted-vmcnt dbuf (r7, for banded K) --------
// Used only by k_av (MODE 2): K window not a multiple of 256.
__device__ __forceinline__ void gemm_core_av(
    int bx, int by,
    const unsigned char* __restrict__ A, int lda,
    const unsigned char* __restrict__ B,
    void* __restrict__ Cout, int ldc, float alpha,
    const unsigned char* __restrict__ A1, const unsigned char* __restrict__ A2,
    unsigned char* __restrict__ smem) {
  int s = bx >> 5, ti = bx & 31;
  const unsigned char* Ab = A + (size_t)by * 128 * lda + s * NSEQ;
  const unsigned char* Bbase = (s == 0) ? B : ((s == 1) ? A1 : A2);
  const unsigned char* Bb = Bbase + (size_t)ti * 128 * 640;
  const int ldbe = 640;
  int lo = ti - 2; if (lo < 0) lo = 0;
  int hi = ti + 3; if (hi > 32) hi = 32;
  int k0 = lo * 128, k1 = hi * 128;
  int b_koff = (ti - 2) * 128;
  int rbase = bx * 128, cbase = by * 128;

  const int t = threadIdx.x;
  const int l = t & 63;
  const int w = t >> 6;
  const int fr = l & 15;
  const int quad = l >> 4;
  const int wm = (w >> 1) * 64;
  const int wn = (w & 1) * 64;
  const int fq4 = quad * 4;

  int srow[4], scg[4], sloff[4];
#pragma unroll
  for (int j = 0; j < 4; j++) {
    srow[j] = w * 32 + j * 8 + (l >> 3);
    scg[j] = ((l & 7) - srow[j]) & 7;
    sloff[j] = (w * 32 + j * 8) * 128 + l * 16;
  }

  f32x4 acc[4][4];
#pragma unroll
  for (int m = 0; m < 4; m++)
#pragma unroll
    for (int n = 0; n < 4; n++) acc[m][n] = (f32x4){0.f, 0.f, 0.f, 0.f};

  const int c0 = quad * 2;
  const int nt = (k1 - k0) >> 7;

  {
    int kk = k0, kb = kk - b_koff;
#pragma unroll
    for (int j = 0; j < 4; j++)
      __builtin_amdgcn_global_load_lds(
          (gvoid_t*)(Ab + (size_t)srow[j] * lda + kk + scg[j] * 16),
          (lvoid_t*)(smem + sloff[j]), 16, 0, 0);
#pragma unroll
    for (int j = 0; j < 4; j++)
      __builtin_amdgcn_global_load_lds(
          (gvoid_t*)(Bb + (size_t)srow[j] * ldbe + kb + scg[j] * 16),
          (lvoid_t*)(smem + 16384 + sloff[j]), 16, 0, 0);
  }

  for (int tt = 0; tt < nt; tt++) {
    if (tt + 1 < nt) {
      int kk = k0 + (tt + 1) * 128, kb = kk - b_koff;
      unsigned char* Asn = smem + ((tt + 1) & 1) * 32768;
#pragma unroll
      for (int j = 0; j < 4; j++)
        __builtin_amdgcn_global_load_lds(
            (gvoid_t*)(Ab + (size_t)srow[j] * lda + kk + scg[j] * 16),
            (lvoid_t*)(Asn + sloff[j]), 16, 0, 0);
#pragma unroll
      for (int j = 0; j < 4; j++)
        __builtin_amdgcn_global_load_lds(
            (gvoid_t*)(Bb + (size_t)srow[j] * ldbe + kb + scg[j] * 16),
            (lvoid_t*)(Asn + 16384 + sloff[j]), 16, 0, 0);
      __builtin_amdgcn_sched_barrier(0);
      asm volatile("s_waitcnt vmcnt(8)" ::: "memory");
    } else {
      asm volatile("s_waitcnt vmcnt(0)" ::: "memory");
    }
    asm volatile("s_barrier" ::: "memory");

    const unsigned char* Asc = smem + (tt & 1) * 32768;
    const unsigned char* Bsc = Asc + 16384;
    int8v a8[4], b8[4];
#pragma unroll
    for (int m = 0; m < 4; m++) {
      int r = wm + m * 16 + fr;
      int s0i = (c0 + r) & 7, s1i = (s0i + 1) & 7;
      a8[m] = pack32(Asc + r * 128 + s0i * 16, Asc + r * 128 + s1i * 16);
    }
#pragma unroll
    for (int n = 0; n < 4; n++) {
      int r = wn + n * 16 + fr;
      int s0i = (c0 + r) & 7, s1i = (s0i + 1) & 7;
      b8[n] = pack32(Bsc + r * 128 + s0i * 16, Bsc + r * 128 + s1i * 16);
    }
#pragma unroll
    for (int m = 0; m < 4; m++)
#pragma unroll
      for (int n = 0; n < 4; n++)
        acc[m][n] = __builtin_amdgcn_mfma_scale_f32_16x16x128_f8f6f4(
            a8[m], b8[n], acc[m][n], 0, 0, 0, 0x7F7F7F7F, 0, 0x7F7F7F7F);
    asm volatile("s_barrier" ::: "memory");
  }

#pragma unroll
  for (int m = 0; m < 4; m++) {
#pragma unroll
    for (int n = 0; n < 4; n++) {
      int oc = cbase + wm + m * 16 + fq4;
      int orow = rbase + wn + n * 16 + fr;
      float v0 = acc[m][n][0] * alpha, v1 = acc[m][n][1] * alpha;
      float v2 = acc[m][n][2] * alpha, v3 = acc[m][n][3] * alpha;
      *(unsigned int*)((unsigned char*)Cout + (size_t)orow * ldc + oc) =
          f2e4x4(v0, v1, v2, v3);
    }
  }
}

// QKV fp8 (BK=256, XCD-swizzled 1D grid of 2304)
__global__ __launch_bounds__(256) void k_qkv(
    const unsigned char* __restrict__ A, const unsigned char* __restrict__ B,
    void* __restrict__ Cout, void* __restrict__ Cout2, float alpha,
    const unsigned char* __restrict__ A1, const unsigned char* __restrict__ A2) {
  __shared__ unsigned char smem[2 * 128 * 256];  // 64 KB: A 32K | B 32K
  int bx, by; xcd_decode(blockIdx.x, bx, by);
  gemm_core256<3, 2, 0>(bx, by, A, 1024, B, 1024, Cout, Cout2, 1024, 1024, alpha,
                        A1, A2, nullptr, smem);
}

// logits -> Eband (exp) + fused band row-sums (BK=256, XCD-swizzled 1D grid of 480)
__global__ __launch_bounds__(256) void k_logits(
    const unsigned char* __restrict__ A, const unsigned char* __restrict__ B,
    void* __restrict__ Cout, float alpha, float* __restrict__ sums) {
  int bx, by; xcd_decode(blockIdx.x, bx, by);
  int ti = bx & 31;
  int bt = ti + by - 2;
  if (bt < 0 || bt >= 32) return;   // whole-block, before any barrier
  __shared__ unsigned char smem[2 * 128 * 256];
  gemm_core256<1, 1, 1>(bx, by, A, 1024, B, 1024, Cout, nullptr, 640, 1024, alpha,
                        nullptr, nullptr, sums, smem);
}

// y = attT @ V (banded K window; r7 core; XCD-swizzled 1D grid of 768)
__global__ __launch_bounds__(256) void k_av(
    const unsigned char* __restrict__ A, const unsigned char* __restrict__ B,
    void* __restrict__ Cout, float alpha,
    const unsigned char* __restrict__ A1, const unsigned char* __restrict__ A2) {
  __shared__ unsigned char smem[4 * 128 * 128];
  int bx, by; xcd_decode(blockIdx.x, bx, by);
  gemm_core_av(bx, by, A, 3 * NSEQ, B, Cout, 1024, alpha, A1, A2, smem);
}

// yo = y @ Wo^T (bf16 out, no exp; BK=256; XCD-swizzled 1D grid of 768)
__global__ __launch_bounds__(256) void k_wo(
    const unsigned char* __restrict__ A, const unsigned char* __restrict__ B,
    void* __restrict__ Cout, float alpha) {
  __shared__ unsigned char smem[2 * 128 * 256];
  int bx, by; xcd_decode(blockIdx.x, bx, by);
  gemm_core256<0, 1, 0>(bx, by, A, 1024, B, 1024, Cout, nullptr, 1024, 1024, alpha,
                        nullptr, nullptr, nullptr, smem);
}

// -------- small bf16 GEMM: 64x64 tile, BK=64, 2-phase dbuf --------
// A = weight (qc dim), B = activation (qr dim).
__global__ __launch_bounds__(256) void k_gemm64(
    const unsigned short* __restrict__ A, int lda,
    const unsigned short* __restrict__ B, int ldb,
    void* __restrict__ Cout, int ldc, int K,
    const float* __restrict__ bias, int relu, int out_bf16) {
  __shared__ unsigned short smem[4 * 64 * 64];  // 32 KB: 2 bufs x (A | B)
  int bx = blockIdx.x, by = blockIdx.y;
  const unsigned short* Ab = A + (size_t)by * 64 * lda;   // weight rows
  const unsigned short* Bb = B + (size_t)bx * 64 * ldb;   // activation rows
  int rbase = bx * 64, cbase = by * 64;

  const int t = threadIdx.x;
  const int l = t & 63;
  const int w = t >> 6;
  const int fr = l & 15;
  const int quad = l >> 4;
  const int wm = (w & 1) * 32;
  const int wn = (w >> 1) * 32;
  const int fq4 = quad * 4;

  int srow[2], scg[2], sloff[2];
#pragma unroll
  for (int j = 0; j < 2; j++) {
    srow[j] = w * 16 + j * 8 + (l >> 3);
    scg[j] = ((l & 7) - srow[j]) & 7;
    sloff[j] = (w * 16 + j * 8) * 64 + l * 8;
  }

  f32x4 acc[2][2];
#pragma unroll
  for (int m = 0; m < 2; m++)
#pragma unroll
    for (int n = 0; n < 2; n++) acc[m][n] = (f32x4){0.f, 0.f, 0.f, 0.f};

  const int nt = K >> 6;

  // prologue: stage tile 0 -> buf 0
#pragma unroll
  for (int j = 0; j < 2; j++)
    __builtin_amdgcn_global_load_lds(
        (gvoid_t*)(Ab + (size_t)srow[j] * lda + scg[j] * 8),
        (lvoid_t*)(smem + sloff[j]), 16, 0, 0);
#pragma unroll
  for (int j = 0; j < 2; j++)
    __builtin_amdgcn_global_load_lds(
        (gvoid_t*)(Bb + (size_t)srow[j] * ldb + scg[j] * 8),
        (lvoid_t*)(smem + 4096 + sloff[j]), 16, 0, 0);

  for (int tt = 0; tt < nt; tt++) {
    __syncthreads();   // buf[tt&1] ready; all waves done reading buf[(tt+1)&1]
    if (tt + 1 < nt) {
      int kk = (tt + 1) * 64;
      unsigned short* Asn = smem + ((tt + 1) & 1) * 8192;
#pragma unroll
      for (int j = 0; j < 2; j++)
        __builtin_amdgcn_global_load_lds(
            (gvoid_t*)(Ab + (size_t)srow[j] * lda + kk + scg[j] * 8),
            (lvoid_t*)(Asn + sloff[j]), 16, 0, 0);
#pragma unroll
      for (int j = 0; j < 2; j++)
        __builtin_amdgcn_global_load_lds(
            (gvoid_t*)(Bb + (size_t)srow[j] * ldb + kk + scg[j] * 8),
            (lvoid_t*)(Asn + 4096 + sloff[j]), 16, 0, 0);
    }
    const unsigned short* Asc = smem + (tt & 1) * 8192;
    const unsigned short* Bsc = Asc + 4096;
#pragma unroll
    for (int s = 0; s < 2; s++) {
      short8 af[2], bf[2];
#pragma unroll
      for (int m = 0; m < 2; m++) {
        int r = wm + m * 16 + fr;
        int slot = (s * 4 + quad + r) & 7;
        af[m] = *(const short8*)(Asc + r * 64 + slot * 8);
      }
#pragma unroll
      for (int n = 0; n < 2; n++) {
        int r = wn + n * 16 + fr;
        int slot = (s * 4 + quad + r) & 7;
        bf[n] = *(const short8*)(Bsc + r * 64 + slot * 8);
      }
#pragma unroll
      for (int m = 0; m < 2; m++)
#pragma unroll
        for (int n = 0; n < 2; n++)
          acc[m][n] = __builtin_amdgcn_mfma_f32_16x16x32_bf16(af[m], bf[n], acc[m][n], 0, 0, 0);
    }
  }

#pragma unroll
  for (int m = 0; m < 2; m++) {
#pragma unroll
    for (int n = 0; n < 2; n++) {
      int oc = cbase + wm + m * 16 + fq4;
      int orow = rbase + wn + n * 16 + fr;
      float4 bv = bias ? *(const float4*)(bias + oc) : make_float4(0.f, 0.f, 0.f, 0.f);
      float v0 = acc[m][n][0] + bv.x, v1 = acc[m][n][1] + bv.y;
      float v2 = acc[m][n][2] + bv.z, v3 = acc[m][n][3] + bv.w;
      if (relu) {
        v0 = fmaxf(v0, 0.f); v1 = fmaxf(v1, 0.f);
        v2 = fmaxf(v2, 0.f); v3 = fmaxf(v3, 0.f);
      }
      if (out_bf16) {
        ushort4 o; o.x = f2b(v0); o.y = f2b(v1); o.z = f2b(v2); o.w = f2b(v3);
        *(uint2*)((unsigned short*)Cout + (size_t)orow * ldc + oc) = *(uint2*)&o;
      } else {
        *(float4*)((float*)Cout + (size_t)orow * ldc + oc) = make_float4(v0, v1, v2, v3);
      }
    }
  }
}

// -------- merged: build banded attT (480 blocks) + write full fp32 att (4096) ----
__global__ __launch_bounds__(256) void k_attw(const unsigned short* __restrict__ Eband,
                                              const float* __restrict__ sums,
                                              unsigned char* __restrict__ t0,
                                              unsigned char* __restrict__ t1,
                                              unsigned char* __restrict__ t2,
                                              float* __restrict__ att) {
  __shared__ unsigned char T[128][132];  // used by build path only
  int bid = blockIdx.x;
  if (bid < 480) {
    int tjoff = bid % 5;                 // was blockIdx.x of k_build_attT
    int byy = bid / 5;                   // was blockIdx.y
    int s = byy >> 5, ti = byy & 31;     // i tile (attT rows), local
    int tj = ti + tjoff - 2;             // j tile
    if (tj < 0 || tj >= 32) return;
    unsigned char* dst = (s == 0) ? t0 : ((s == 1) ? t1 : t2);
    int t = threadIdx.x;
    int c0 = (ti - tj + 2) * 128;  // Eband col base for rows j reading i-tile ti
    int colg = (t & 31) * 4;       // i_loc
    for (int jj = t >> 5; jj < 128; jj += 8) {
      int jg = s * NSEQ + tj * 128 + jj;
      float inv = 16.f / sums[jg];
      ushort4 v = *(const ushort4*)&Eband[(size_t)jg * 640 + c0 + colg];
      float vv[4] = {b2f(v.x), b2f(v.y), b2f(v.z), b2f(v.w)};
#pragma unroll
      for (int q = 0; q < 4; q++) {
        int i = ti * 128 + colg + q;
        int d = i - (tj * 128 + jj);
        float a = (d < 250 && d > -250) ? vv[q] * inv : 0.f;
        T[colg + q][jj] = f2e4(a);
      }
    }
    __syncthreads();
    int jb0 = (tj - ti + 2) * 128;  // banded col base in attT rows of tile ti
    for (int ii = t >> 5; ii < 128; ii += 8) {
      size_t o = (size_t)(ti * 128 + ii) * 640 + jb0 + colg;
      *(unsigned int*)(dst + o) = *(const unsigned int*)&T[ii][colg];
    }
  } else {
    int i = bid - 480;                   // row 0..4095
    int ti = i >> 7, cbase = (ti - 2) * 128;
    int jlo = i - 249; if (jlo < 0) jlo = 0;
    int jhi = i + 249; if (jhi > NSEQ - 1) jhi = NSEQ - 1;
    float inv = 1.f / sums[i];
    const unsigned short* L = Eband + (size_t)i * 640;
    float* arow = att + (size_t)i * NSEQ;
    for (int j0 = threadIdx.x * 4; j0 < NSEQ; j0 += 1024) {
      float ov[4];
#pragma unroll
      for (int q = 0; q < 4; q++) {
        int j = j0 + q;
        ov[q] = (j >= jlo && j <= jhi) ? b2f(L[j - cbase]) * inv : 0.f;
      }
      *(float4*)(arow + j0) = make_float4(ov[0], ov[1], ov[2], ov[3]);
    }
  }
}

// -------- residual + LayerNorm (ddof=1, eps on std) for 3 streams, sum -> bf16 --------
__global__ __launch_bounds__(256) void k_ln3(const unsigned short* __restrict__ yo,
                                             const float* __restrict__ x1,
                                             const float* __restrict__ x2,
                                             const float* __restrict__ x3,
                                             const float* __restrict__ g,
                                             const float* __restrict__ b,
                                             unsigned short* __restrict__ ysum_b) {
  int i = blockIdx.x, t = threadIdx.x;
  int w = t >> 6, lane = t & 63;
  __shared__ float red[8];
  const float* xs[3] = {x1, x2, x3};
  float4 gg = *(const float4*)(g + t * 4);
  float4 bb = *(const float4*)(b + t * 4);
  float acc[4] = {0.f, 0.f, 0.f, 0.f};
  for (int s = 0; s < 3; s++) {
    ushort4 yv = *(const ushort4*)(yo + ((size_t)(s * NSEQ + i)) * MDIM + t * 4);
    float4 xx = *(const float4*)(xs[s] + (size_t)i * MDIM + t * 4);
    float v[4] = {b2f(yv.x) + xx.x, b2f(yv.y) + xx.y, b2f(yv.z) + xx.z, b2f(yv.w) + xx.w};
    float s1 = v[0] + v[1] + v[2] + v[3];
    float s2 = v[0]*v[0] + v[1]*v[1] + v[2]*v[2] + v[3]*v[3];
    for (int off = 32; off; off >>= 1) { s1 += __shfl_xor(s1, off); s2 += __shfl_xor(s2, off); }
    __syncthreads();
    if (lane == 0) { red[w] = s1; red[4 + w] = s2; }
    __syncthreads();
    float S1 = red[0] + red[1] + red[2] + red[3];
    float S2 = red[4] + red[5] + red[6] + red[7];
    float mean = S1 * (1.f / 1024.f);
    float var = (S2 - S1 * mean) * (1.f / 1023.f);
    float rstd = 1.f / (sqrtf(var) + 1e-6f);
    acc[0] += gg.x * (v[0] - mean) * rstd + bb.x;
    acc[1] += gg.y * (v[1] - mean) * rstd + bb.y;
    acc[2] += gg.z * (v[2] - mean) * rstd + bb.z;
    acc[3] += gg.w * (v[3] - mean) * rstd + bb.w;
  }
  ushort4 o;
  o.x = f2b(acc[0]); o.y = f2b(acc[1]); o.z = f2b(acc[2]); o.w = f2b(acc[3]);
  *(ushort4*)(ysum_b + (size_t)i * MDIM + t * 4) = o;
}

// -------- final: LN(128, gkc/bkc) -> dot(kd_w) + kd_b -> sigmoid --------
__global__ __launch_bounds__(128) void k_final(const float* __restrict__ h3,
                                               const float* __restrict__ g,
                                               const float* __restrict__ b,
                                               const float* __restrict__ kdw,
                                               const float* __restrict__ kdb,
                                               float* __restrict__ yout) {
  int i = blockIdx.x, t = threadIdx.x;
  float v = h3[(size_t)i * 128 + t];
  float s1 = v, s2 = v * v;
  for (int off = 32; off; off >>= 1) { s1 += __shfl_xor(s1, off); s2 += __shfl_xor(s2, off); }
  __shared__ float red[4];
  int w = t >> 6, lane = t & 63;
  if (lane == 0) { red[w] = s1; red[2 + w] = s2; }
  __syncthreads();
  float S1 = red[0] + red[1], S2 = red[2] + red[3];
  float mean = S1 * (1.f / 128.f);
  float var = (S2 - S1 * mean) * (1.f / 127.f);
  float rstd = 1.f / (sqrtf(var) + 1e-6f);
  float ln = g[t] * (v - mean) * rstd + b[t];
  float p = ln * kdw[t];
  for (int off = 32; off; off >>= 1) p += __shfl_xor(p, off);
  __syncthreads();
  if (lane == 0) red[w] = p;
  __syncthreads();
  if (t == 0) {
    float z = red[0] + red[1] + kdb[0];
    yout[i] = 1.f / (1.f + __expf(-z));
  }
}

extern "C" void kernel_launch(void* const* d_in, const int* in_sizes, int n_in,
                              void* d_out, int out_size, void* d_ws, size_t ws_size,
                              hipStream_t stream) {
  const float* x1 = (const float*)d_in[0];
  const float* x2 = (const float*)d_in[1];
  const float* x3 = (const float*)d_in[2];
  const float* Wq = (const float*)d_in[3];
  const float* Wk = (const float*)d_in[4];
  const float* Wv = (const float*)d_in[5];
  const float* Wo = (const float*)d_in[6];
  const float* ka_w = (const float*)d_in[7];
  const float* ka_b = (const float*)d_in[8];
  const float* kb_w = (const float*)d_in[9];
  const float* kb_b = (const float*)d_in[10];
  const float* kc_w = (const float*)d_in[11];
  const float* kc_b = (const float*)d_in[12];
  const float* kd_w = (const float*)d_in[13];
  const float* kd_b = (const float*)d_in[14];
  const float* g13 = (const float*)d_in[15];
  const float* b13 = (const float*)d_in[16];
  const float* gkc = (const float*)d_in[17];
  const float* bkc = (const float*)d_in[18];

  float* y_out = (float*)d_out;
  float* att_out = y_out + NSEQ;  // [4096,4096] fp32

  char* ws = (char*)d_ws;
  size_t off = 0;
  auto alloc = [&](size_t bytes) -> void* {
    void* p = ws + off;
    off += (bytes + 255) & ~(size_t)255;
    return p;
  };
  const size_t NM = (size_t)3 * NSEQ * MDIM;  // 12.6M elems
  // fp8 attention weights, contiguous: Wq|Wk|Wv|Wo (x64 scaled)
  unsigned char* Wf = (unsigned char*)alloc(4 * 1048576);
  // bf16 MLP weights, contiguous: ka|kb|kc
  unsigned short* Wmlp = (unsigned short*)alloc((1048576 + 524288 + 65536) * 2);
  unsigned char* Xf = (unsigned char*)alloc(NM);      // later: yb fp8, then h1b bf16
  unsigned char* Qf = (unsigned char*)alloc(NM);      // yo bf16 spans Qf+Kf; later h2b
  unsigned char* Kf = (unsigned char*)alloc(NM);
  unsigned char* VTf = (unsigned char*)alloc(NM);     // later: ysum_b bf16 (8MB)
  unsigned short* Eband = (unsigned short*)alloc((size_t)3 * NSEQ * 640 * 2);
  float* sums = (float*)alloc((size_t)3 * NSEQ * 4);
  unsigned char* aT0 = (unsigned char*)alloc((size_t)NSEQ * 640);  // later: h3 f32
  unsigned char* aT1 = (unsigned char*)alloc((size_t)NSEQ * 640);
  unsigned char* aT2 = (unsigned char*)alloc((size_t)NSEQ * 640);
  // weight sub-pointers
  unsigned char* Wv_f = Wf + 2097152;
  unsigned char* Wo_f = Wf + 3145728;
  unsigned short* ka_b16 = Wmlp;
  unsigned short* kb_b16 = Wmlp + 1048576;
  unsigned short* kc_b16 = Wmlp + 1572864;
  // aliases (lifetimes disjoint)
  unsigned char* yb = Xf;                       // fp8 [12288,1024] = 8*y
  unsigned short* yo = (unsigned short*)Qf;     // bf16 [12288,1024] spans Qf..Kf
  unsigned short* ysum_b = (unsigned short*)VTf;// bf16 [4096,1024]
  unsigned short* h1b = (unsigned short*)Xf;    // bf16 [4096,1024]
  unsigned short* h2b = (unsigned short*)Qf;    // bf16 [4096,512]
  float* h3 = (float*)aT0;                      // f32 [4096,128]

  // all conversions + sums zero-init in one dispatch
  k_cvt_all<<<17996, 256, 0, stream>>>(Wq, Wk, Wv, Wo, ka_w, kb_w, kc_w,
                                       x1, x2, x3, Wf, Wmlp, Xf, sums);

  // merged Q+K+VT fp8: Q/K: A=Wq|Wk, B=X; VT: A=X, B=Wv (XCD-swizzled)
  k_qkv<<<2304, 256, 0, stream>>>(Wf, Xf, Qf, Kf, 1.f / 64.f, Wv_f, VTf);
  // banded logits -> E = exp(0.06 * Q.K) bf16 [12288,640] + fused band row-sums
  k_logits<<<480, 256, 0, stream>>>(Kf, Qf, Eband, 0.06f, sums);
  // merged: banded attT build + full fp32 att write
  k_attw<<<4576, 256, 0, stream>>>(Eband, sums, aT0, aT1, aT2, att_out);
  // yb = 8*y: A=VT (v minor), B=attT banded; (16att)@V * 0.5, fp8 out
  k_av<<<768, 256, 0, stream>>>(VTf, aT0, yb, 0.5f, aT1, aT2);
  // yo = y @ Wo^T (bf16 out): A=Wo, B=y; (8y)@(64Wo) * 1/512
  k_wo<<<768, 256, 0, stream>>>(Wo_f, yb, yo, 1.f / 512.f);
  // residual + LN + 3-stream sum -> bf16
  k_ln3<<<4096, 256, 0, stream>>>(yo, x1, x2, x3, g13, b13, ysum_b);

  // MLP head (bf16, 64x64 tiles dbuf, A=weight)
  k_gemm64<<<dim3(64, 16), 256, 0, stream>>>(ka_b16, 1024, ysum_b, 1024, h1b, 1024,
                                             1024, ka_b, 0, 1);
  k_gemm64<<<dim3(64, 8), 256, 0, stream>>>(kb_b16, 1024, h1b, 1024, h2b, 512,
                                            1024, kb_b, 0, 1);
  k_gemm64<<<dim3(64, 2), 256, 0, stream>>>(kc_b16, 512, h2b, 512, h3, 128,
                                            512, kc_b, 1, 0);
  k_final<<<4096, 128, 0, stream>>>(h3, gkc, bkc, kd_w, kd_b, y_out);
}